// Round 4
// baseline (2934.442 us; speedup 1.0000x reference)
//
#include <hip/hip_runtime.h>

// APPNP link-prediction: N=100000 nodes, F=256 in, H=128 hidden,
// E=1.6M edges, K=10 hops x 2 layers, alpha=0.1, decode over 800K edges.
// All fp32. CSR-by-dst (self-loops folded, 0.9*norm pre-folded into w),
// gather-only SpMV hops with forced 16-deep MLP (static-indexed unroll).

constexpr int Hd = 128;       // hidden dim
constexpr int Fin = 256;      // input feature dim
constexpr float A_ = 0.1f;    // alpha
constexpr float OMA = 0.9f;   // 1 - alpha

__device__ __forceinline__ int idx_at(const void* p, size_t i, int is64) {
    if (is64) return (int)((const long long*)p)[i];
    return ((const int*)p)[i];
}

// ---------------- dtype probe ----------------
__global__ void k_detect(const int* __restrict__ p, int npairs, int* __restrict__ flag) {
    __shared__ int any32;
    if (threadIdx.x == 0) any32 = 0;
    __syncthreads();
    for (int i = threadIdx.x; i < npairs; i += blockDim.x)
        if (p[2 * i + 1] != 0) any32 = 1;
    __syncthreads();
    if (threadIdx.x == 0) *flag = any32 ? 0 : 1;   // 1 => int64
}

// ---------------- preprocessing ----------------

__global__ void k_zero_i32(int* __restrict__ p, int n) {
    int i = blockIdx.x * blockDim.x + threadIdx.x;
    if (i < n) p[i] = 0;
}

__global__ void k_count(const void* __restrict__ ei, int E, int* __restrict__ cnt,
                        const int* __restrict__ flag) {
    int is64 = *flag;
    int e = blockIdx.x * blockDim.x + threadIdx.x;
    if (e < E) {
        int d = idx_at(ei, (size_t)E + e, is64);
        atomicAdd(&cnt[d], 1);
    }
}

__global__ void k_dinv(const int* __restrict__ cnt, float* __restrict__ dinv, int N) {
    int i = blockIdx.x * blockDim.x + threadIdx.x;
    if (i < N) dinv[i] = rsqrtf((float)(cnt[i] + 1));
}

__global__ void k_scan1(const int* __restrict__ cnt, int* __restrict__ rp,
                        int* __restrict__ bsum, int N) {
    __shared__ int s[256];
    int t = threadIdx.x;
    int i = blockIdx.x * 256 + t;
    int v = (i < N) ? (cnt[i] + 1) : 0;   // +1 self-loop slot
    s[t] = v;
    __syncthreads();
    for (int off = 1; off < 256; off <<= 1) {
        int add = (t >= off) ? s[t - off] : 0;
        __syncthreads();
        s[t] += add;
        __syncthreads();
    }
    if (i < N) rp[i] = s[t] - v;
    if (t == 255) bsum[blockIdx.x] = s[255];
}

__global__ void k_scan2(int* __restrict__ bsum, int nb) {
    __shared__ int s[512];
    int t = threadIdx.x;
    int v = (t < nb) ? bsum[t] : 0;
    s[t] = v;
    __syncthreads();
    for (int off = 1; off < 512; off <<= 1) {
        int add = (t >= off) ? s[t - off] : 0;
        __syncthreads();
        s[t] += add;
        __syncthreads();
    }
    if (t < nb) bsum[t] = s[t] - v;
}

__global__ void k_scan3(int* __restrict__ rp, const int* __restrict__ bsum,
                        int* __restrict__ cursor, const float* __restrict__ dinv,
                        int2* __restrict__ cw, int N, int Etot) {
    int i = blockIdx.x * blockDim.x + threadIdx.x;
    if (i < N) {
        int r = rp[i] + bsum[i >> 8];
        rp[i] = r;
        cursor[i] = 1;
        float d = dinv[i];
        int2 p;
        p.x = i;
        p.y = __float_as_int(OMA * d * d);
        cw[r] = p;   // self-loop first in each row
    }
    if (i == 0) rp[N] = Etot;
}

__global__ void k_place(const void* __restrict__ ei, int E,
                        const int* __restrict__ rp, int* __restrict__ cursor,
                        const float* __restrict__ dinv,
                        int2* __restrict__ cw, const int* __restrict__ flag) {
    int is64 = *flag;
    int e = blockIdx.x * blockDim.x + threadIdx.x;
    if (e < E) {
        int s = idx_at(ei, (size_t)e, is64);
        int d = idx_at(ei, (size_t)E + e, is64);
        int pos = rp[d] + atomicAdd(&cursor[d], 1);
        int2 p;
        p.x = s;
        p.y = __float_as_int(OMA * dinv[s] * dinv[d]);
        cw[pos] = p;
    }
}

// ---------------- GEMM: C[N][128] = act(A)[N][KTOT] @ B[KTOT][128] ----------------

template <int KTOT, bool RELU>
__global__ __launch_bounds__(256) void k_gemm(const float* __restrict__ A,
                                              const float* __restrict__ B,
                                              float* __restrict__ C, int N) {
    __shared__ float As[64][36];
    __shared__ float Bs[32][128];
    const int t  = threadIdx.x;
    const int tx = t & 15;
    const int ty = t >> 4;
    const int r0 = blockIdx.x * 64;

    float acc[4][8];
#pragma unroll
    for (int i = 0; i < 4; ++i)
#pragma unroll
        for (int j = 0; j < 8; ++j) acc[i][j] = 0.f;

    for (int k0 = 0; k0 < KTOT; k0 += 32) {
#pragma unroll
        for (int p = 0; p < 2; ++p) {
            int row = p * 32 + (t >> 3);
            int kk  = (t & 7) * 4;
            int gr  = r0 + row;
            float4 v = make_float4(0.f, 0.f, 0.f, 0.f);
            if (gr < N) v = *(const float4*)&A[(size_t)gr * KTOT + k0 + kk];
            if (RELU) {
                v.x = fmaxf(v.x, 0.f); v.y = fmaxf(v.y, 0.f);
                v.z = fmaxf(v.z, 0.f); v.w = fmaxf(v.w, 0.f);
            }
            *(float4*)&As[row][kk] = v;
        }
#pragma unroll
        for (int p = 0; p < 4; ++p) {
            int kr = p * 8 + (t >> 5);
            int c  = (t & 31) * 4;
            *(float4*)&Bs[kr][c] = *(const float4*)&B[(size_t)(k0 + kr) * Hd + c];
        }
        __syncthreads();
#pragma unroll
        for (int kk = 0; kk < 32; ++kk) {
            float a[4];
#pragma unroll
            for (int i = 0; i < 4; ++i) a[i] = As[ty * 4 + i][kk];
            float4 b0 = *(const float4*)&Bs[kk][tx * 8];
            float4 b1 = *(const float4*)&Bs[kk][tx * 8 + 4];
            float b[8] = {b0.x, b0.y, b0.z, b0.w, b1.x, b1.y, b1.z, b1.w};
#pragma unroll
            for (int i = 0; i < 4; ++i)
#pragma unroll
                for (int j = 0; j < 8; ++j) acc[i][j] = fmaf(a[i], b[j], acc[i][j]);
        }
        __syncthreads();
    }
#pragma unroll
    for (int i = 0; i < 4; ++i) {
        int gr = r0 + ty * 4 + i;
        if (gr < N) {
            *(float4*)&C[(size_t)gr * Hd + tx * 8]     = make_float4(acc[i][0], acc[i][1], acc[i][2], acc[i][3]);
            *(float4*)&C[(size_t)gr * Hd + tx * 8 + 4] = make_float4(acc[i][4], acc[i][5], acc[i][6], acc[i][7]);
        }
    }
}

// ---------------- propagation hop ----------------
// wave-per-node; lane holds float2; forced 16-deep gather batches.

template <int B>
__device__ __forceinline__ void hop_batch(const float2* __restrict__ zf,
                                          const int2* __restrict__ cw,
                                          int e, int lane,
                                          float& ax, float& ay,
                                          float& bx, float& by) {
    int2 p[B];
#pragma unroll
    for (int k = 0; k < B; ++k) p[k] = cw[e + k];
    float2 zv[B];
#pragma unroll
    for (int k = 0; k < B; ++k) zv[k] = zf[((unsigned)p[k].x << 6) + lane];
#pragma unroll
    for (int k = 0; k < B; ++k) {
        float wv = __int_as_float(p[k].y);
        if (k & 1) { bx = fmaf(wv, zv[k].x, bx); by = fmaf(wv, zv[k].y, by); }
        else       { ax = fmaf(wv, zv[k].x, ax); ay = fmaf(wv, zv[k].y, ay); }
    }
}

__global__ __launch_bounds__(256) void k_hop(const float* __restrict__ zin,
                                             const float* __restrict__ h,
                                             float* __restrict__ zout,
                                             const int* __restrict__ rp,
                                             const int2* __restrict__ cw, int N) {
    int wid  = (blockIdx.x * blockDim.x + threadIdx.x) >> 6;
    int lane = threadIdx.x & 63;
    if (wid >= N) return;
    const float2* zf = (const float2*)zin;

    int e   = __builtin_amdgcn_readfirstlane(rp[wid]);
    int end = __builtin_amdgcn_readfirstlane(rp[wid + 1]);

    // prefetch teleport term early (independent of loop)
    float2 hh = *(const float2*)&h[((size_t)wid << 7) + lane * 2];

    float ax = 0.f, ay = 0.f, bx = 0.f, by = 0.f;

    for (; e + 16 <= end; e += 16)
        hop_batch<16>(zf, cw, e, lane, ax, ay, bx, by);
    if (e + 8 <= end) { hop_batch<8>(zf, cw, e, lane, ax, ay, bx, by); e += 8; }
    if (e + 4 <= end) { hop_batch<4>(zf, cw, e, lane, ax, ay, bx, by); e += 4; }
    for (; e < end; ++e) {
        int2 p = cw[e];
        float2 zv = zf[((unsigned)p.x << 6) + lane];
        float wv = __int_as_float(p.y);
        ax = fmaf(wv, zv.x, ax); ay = fmaf(wv, zv.y, ay);
    }

    float2 o;
    o.x = (ax + bx) + A_ * hh.x;
    o.y = (ay + by) + A_ * hh.y;
    *(float2*)&zout[((size_t)wid << 7) + lane * 2] = o;
}

// ---------------- decode: out[j] = dot(z[e0[j]], z[e1[j]]) ----------------

__global__ __launch_bounds__(256) void k_decode(const float* __restrict__ z,
                                                const void* __restrict__ pos,
                                                const void* __restrict__ neg,
                                                float* __restrict__ out, int P, int Q,
                                                const int* __restrict__ flag) {
    int is64 = *flag;
    int t   = blockIdx.x * blockDim.x + threadIdx.x;
    int j   = t >> 4;
    int sub = t & 15;
    if (j >= P + Q) return;
    int a, b;
    if (j < P) { a = idx_at(pos, (size_t)j, is64); b = idx_at(pos, (size_t)P + j, is64); }
    else       { int jj = j - P; a = idx_at(neg, (size_t)jj, is64); b = idx_at(neg, (size_t)Q + jj, is64); }
    const float4* za = (const float4*)&z[(size_t)a * Hd];
    const float4* zb = (const float4*)&z[(size_t)b * Hd];
    float s = 0.f;
#pragma unroll
    for (int q = 0; q < 2; ++q) {
        float4 va = za[q * 16 + sub];
        float4 vb = zb[q * 16 + sub];
        s += va.x * vb.x + va.y * vb.y + va.z * vb.z + va.w * vb.w;
    }
#pragma unroll
    for (int off = 8; off >= 1; off >>= 1) s += __shfl_xor(s, off, 16);
    if (sub == 0) out[j] = s;
}

// ---------------- launch ----------------

extern "C" void kernel_launch(void* const* d_in, const int* in_sizes, int n_in,
                              void* d_out, int out_size, void* d_ws, size_t ws_size,
                              hipStream_t stream) {
    const float* x   = (const float*)d_in[0];
    const void*  ei  = d_in[1];
    const void*  pos = d_in[2];
    const void*  neg = d_in[3];
    const float* W1  = (const float*)d_in[4];
    const float* W2  = (const float*)d_in[5];
    float*       out = (float*)d_out;

    const int N = in_sizes[0] / Fin;
    const int E = in_sizes[1] / 2;
    const int P = in_sizes[2] / 2;
    const int Q = in_sizes[3] / 2;
    const int Etot = E + N;

    char*  ws  = (char*)d_ws;
    size_t off = 0;
    auto carve = [&](size_t bytes) -> void* {
        void* p = ws + off;
        off = (off + bytes + 511) & ~(size_t)511;
        return p;
    };
    float* h      = (float*)carve((size_t)N * Hd * 4);
    float* zA     = (float*)carve((size_t)N * Hd * 4);
    float* zB     = (float*)carve((size_t)N * Hd * 4);
    float* dinv   = (float*)carve((size_t)N * 4);
    int*   cnt    = (int*)carve((size_t)N * 4);
    int*   rp     = (int*)carve((size_t)(N + 1) * 4);
    int*   cursor = (int*)carve((size_t)N * 4);
    int2*  cw     = (int2*)carve((size_t)Etot * 8);
    int    nb     = (N + 255) / 256;
    int*   bsum   = (int*)carve((size_t)nb * 4);
    int*   flag   = (int*)carve(4);
    (void)ws_size;

    const int gN = (N + 255) / 256;
    const int gE = (E + 255) / 256;

    k_detect<<<1, 256, 0, stream>>>((const int*)ei, 4096, flag);
    k_zero_i32<<<gN, 256, 0, stream>>>(cnt, N);
    k_count<<<gE, 256, 0, stream>>>(ei, E, cnt, flag);
    k_dinv<<<gN, 256, 0, stream>>>(cnt, dinv, N);
    k_scan1<<<nb, 256, 0, stream>>>(cnt, rp, bsum, N);
    k_scan2<<<1, 512, 0, stream>>>(bsum, nb);
    k_scan3<<<gN, 256, 0, stream>>>(rp, bsum, cursor, dinv, cw, N, Etot);
    k_place<<<gE, 256, 0, stream>>>(ei, E, rp, cursor, dinv, cw, flag);

    const int gGemm = (N + 63) / 64;
    const int gHop  = (N * 64 + 255) / 256;

    // ---- layer 1: h = x @ W1; 10 hops ----
    k_gemm<Fin, false><<<gGemm, 256, 0, stream>>>(x, W1, h, N);
    {
        float* bufs[2] = {zA, zB};
        const float* zin = h;
        for (int k = 0; k < 10; ++k) {
            float* zout = bufs[k & 1];
            k_hop<<<gHop, 256, 0, stream>>>(zin, h, zout, rp, cw, N);
            zin = zout;
        }
    }
    // ---- layer 2: h = relu(zB) @ W2; 10 hops ----
    k_gemm<Hd, true><<<gGemm, 256, 0, stream>>>(zB, W2, h, N);
    {
        float* bufs[2] = {zA, zB};
        const float* zin = h;
        for (int k = 0; k < 10; ++k) {
            float* zout = bufs[k & 1];
            k_hop<<<gHop, 256, 0, stream>>>(zin, h, zout, rp, cw, N);
            zin = zout;
        }
    }
    // ---- decode ----
    const int gDec = ((P + Q) * 16 + 255) / 256;
    k_decode<<<gDec, 256, 0, stream>>>(zB, pos, neg, out, P, Q, flag);
}

// Round 5
// 1764.536 us; speedup vs baseline: 1.6630x; 1.6630x over previous
//
#include <hip/hip_runtime.h>

// APPNP link-prediction: N=100000, F=256, H=128, E=1.6M, K=10 x 2 layers.
// CSR-by-dst (self-loops folded, 0.9*norm pre-folded), gather-only SpMV hops.
// z stored as bf16 (256B rows) during propagation -> halves gather traffic;
// accumulation + teleport + final-hop output stay fp32.

constexpr int Hd = 128;
constexpr int Fin = 256;
constexpr float A_ = 0.1f;
constexpr float OMA = 0.9f;

__device__ __forceinline__ int idx_at(const void* p, size_t i, int is64) {
    if (is64) return (int)((const long long*)p)[i];
    return ((const int*)p)[i];
}

__device__ __forceinline__ unsigned pack_bf16x2(float x, float y) {
    unsigned ux = __float_as_uint(x);
    unsigned uy = __float_as_uint(y);
    ux = (ux + 0x7fffu + ((ux >> 16) & 1u)) >> 16;          // RNE
    uy = (uy + 0x7fffu + ((uy >> 16) & 1u)) & 0xffff0000u;  // RNE, keep high
    return ux | uy;
}

__device__ __forceinline__ float2 unpack_bf16x2(unsigned v) {
    float2 r;
    r.x = __uint_as_float(v << 16);
    r.y = __uint_as_float(v & 0xffff0000u);
    return r;
}

// ---------------- dtype probe ----------------
__global__ void k_detect(const int* __restrict__ p, int npairs, int* __restrict__ flag) {
    __shared__ int any32;
    if (threadIdx.x == 0) any32 = 0;
    __syncthreads();
    for (int i = threadIdx.x; i < npairs; i += blockDim.x)
        if (p[2 * i + 1] != 0) any32 = 1;
    __syncthreads();
    if (threadIdx.x == 0) *flag = any32 ? 0 : 1;   // 1 => int64
}

// ---------------- preprocessing ----------------

__global__ void k_zero_i32(int* __restrict__ p, int n) {
    int i = blockIdx.x * blockDim.x + threadIdx.x;
    if (i < n) p[i] = 0;
}

__global__ void k_count(const void* __restrict__ ei, int E, int* __restrict__ cnt,
                        const int* __restrict__ flag) {
    int is64 = *flag;
    int e = blockIdx.x * blockDim.x + threadIdx.x;
    if (e < E) {
        int d = idx_at(ei, (size_t)E + e, is64);
        atomicAdd(&cnt[d], 1);
    }
}

__global__ void k_dinv(const int* __restrict__ cnt, float* __restrict__ dinv, int N) {
    int i = blockIdx.x * blockDim.x + threadIdx.x;
    if (i < N) dinv[i] = rsqrtf((float)(cnt[i] + 1));
}

__global__ void k_scan1(const int* __restrict__ cnt, int* __restrict__ rp,
                        int* __restrict__ bsum, int N) {
    __shared__ int s[256];
    int t = threadIdx.x;
    int i = blockIdx.x * 256 + t;
    int v = (i < N) ? (cnt[i] + 1) : 0;   // +1 self-loop slot
    s[t] = v;
    __syncthreads();
    for (int off = 1; off < 256; off <<= 1) {
        int add = (t >= off) ? s[t - off] : 0;
        __syncthreads();
        s[t] += add;
        __syncthreads();
    }
    if (i < N) rp[i] = s[t] - v;
    if (t == 255) bsum[blockIdx.x] = s[255];
}

__global__ void k_scan2(int* __restrict__ bsum, int nb) {
    __shared__ int s[512];
    int t = threadIdx.x;
    int v = (t < nb) ? bsum[t] : 0;
    s[t] = v;
    __syncthreads();
    for (int off = 1; off < 512; off <<= 1) {
        int add = (t >= off) ? s[t - off] : 0;
        __syncthreads();
        s[t] += add;
        __syncthreads();
    }
    if (t < nb) bsum[t] = s[t] - v;
}

__global__ void k_scan3(int* __restrict__ rp, const int* __restrict__ bsum,
                        int* __restrict__ cursor, const float* __restrict__ dinv,
                        int2* __restrict__ cw, int N, int Etot) {
    int i = blockIdx.x * blockDim.x + threadIdx.x;
    if (i < N) {
        int r = rp[i] + bsum[i >> 8];
        rp[i] = r;
        cursor[i] = 1;
        float d = dinv[i];
        int2 p;
        p.x = i;
        p.y = __float_as_int(OMA * d * d);
        cw[r] = p;   // self-loop first in each row
    }
    if (i == 0) rp[N] = Etot;
}

__global__ void k_place(const void* __restrict__ ei, int E,
                        const int* __restrict__ rp, int* __restrict__ cursor,
                        const float* __restrict__ dinv,
                        int2* __restrict__ cw, const int* __restrict__ flag) {
    int is64 = *flag;
    int e = blockIdx.x * blockDim.x + threadIdx.x;
    if (e < E) {
        int s = idx_at(ei, (size_t)e, is64);
        int d = idx_at(ei, (size_t)E + e, is64);
        int pos = rp[d] + atomicAdd(&cursor[d], 1);
        int2 p;
        p.x = s;
        p.y = __float_as_int(OMA * dinv[s] * dinv[d]);
        cw[pos] = p;
    }
}

// ---------------- fp32 -> bf16x2 convert: [N][128] f32 -> [N][64] u32 ----------------
__global__ __launch_bounds__(256) void k_cvt(const float* __restrict__ in,
                                             unsigned* __restrict__ out, int n64) {
    int i = blockIdx.x * blockDim.x + threadIdx.x;
    if (i < n64) {
        float2 v = ((const float2*)in)[i];
        out[i] = pack_bf16x2(v.x, v.y);
    }
}

// ---------------- GEMM: C[N][128] = act(A)[N][KTOT] @ B[KTOT][128] ----------------

template <int KTOT, bool RELU>
__global__ __launch_bounds__(256) void k_gemm(const float* __restrict__ A,
                                              const float* __restrict__ B,
                                              float* __restrict__ C, int N) {
    __shared__ float As[64][36];
    __shared__ float Bs[32][128];
    const int t  = threadIdx.x;
    const int tx = t & 15;
    const int ty = t >> 4;
    const int r0 = blockIdx.x * 64;

    float acc[4][8];
#pragma unroll
    for (int i = 0; i < 4; ++i)
#pragma unroll
        for (int j = 0; j < 8; ++j) acc[i][j] = 0.f;

    for (int k0 = 0; k0 < KTOT; k0 += 32) {
#pragma unroll
        for (int p = 0; p < 2; ++p) {
            int row = p * 32 + (t >> 3);
            int kk  = (t & 7) * 4;
            int gr  = r0 + row;
            float4 v = make_float4(0.f, 0.f, 0.f, 0.f);
            if (gr < N) v = *(const float4*)&A[(size_t)gr * KTOT + k0 + kk];
            if (RELU) {
                v.x = fmaxf(v.x, 0.f); v.y = fmaxf(v.y, 0.f);
                v.z = fmaxf(v.z, 0.f); v.w = fmaxf(v.w, 0.f);
            }
            *(float4*)&As[row][kk] = v;
        }
#pragma unroll
        for (int p = 0; p < 4; ++p) {
            int kr = p * 8 + (t >> 5);
            int c  = (t & 31) * 4;
            *(float4*)&Bs[kr][c] = *(const float4*)&B[(size_t)(k0 + kr) * Hd + c];
        }
        __syncthreads();
#pragma unroll
        for (int kk = 0; kk < 32; ++kk) {
            float a[4];
#pragma unroll
            for (int i = 0; i < 4; ++i) a[i] = As[ty * 4 + i][kk];
            float4 b0 = *(const float4*)&Bs[kk][tx * 8];
            float4 b1 = *(const float4*)&Bs[kk][tx * 8 + 4];
            float b[8] = {b0.x, b0.y, b0.z, b0.w, b1.x, b1.y, b1.z, b1.w};
#pragma unroll
            for (int i = 0; i < 4; ++i)
#pragma unroll
                for (int j = 0; j < 8; ++j) acc[i][j] = fmaf(a[i], b[j], acc[i][j]);
        }
        __syncthreads();
    }
#pragma unroll
    for (int i = 0; i < 4; ++i) {
        int gr = r0 + ty * 4 + i;
        if (gr < N) {
            *(float4*)&C[(size_t)gr * Hd + tx * 8]     = make_float4(acc[i][0], acc[i][1], acc[i][2], acc[i][3]);
            *(float4*)&C[(size_t)gr * Hd + tx * 8 + 4] = make_float4(acc[i][4], acc[i][5], acc[i][6], acc[i][7]);
        }
    }
}

// ---------------- propagation hop (bf16 gather, fp32 accum) ----------------
// wave-per-node; lane holds 2 features as one u32; 16-deep gather batches.

template <int B>
__device__ __forceinline__ void hop_batch(const unsigned* __restrict__ zb,
                                          const int2* __restrict__ cw,
                                          int e, int lane,
                                          float& ax, float& ay,
                                          float& bx, float& by) {
    int2 p[B];
#pragma unroll
    for (int k = 0; k < B; ++k) p[k] = cw[e + k];
    unsigned zv[B];
#pragma unroll
    for (int k = 0; k < B; ++k) zv[k] = zb[((unsigned)p[k].x << 6) + lane];
#pragma unroll
    for (int k = 0; k < B; ++k) {
        float wv = __int_as_float(p[k].y);
        float2 z = unpack_bf16x2(zv[k]);
        if (k & 1) { bx = fmaf(wv, z.x, bx); by = fmaf(wv, z.y, by); }
        else       { ax = fmaf(wv, z.x, ax); ay = fmaf(wv, z.y, ay); }
    }
}

template <bool OUTF32>
__global__ __launch_bounds__(256) void k_hop(const unsigned* __restrict__ zin,
                                             const float* __restrict__ h,
                                             unsigned* __restrict__ zout_b,
                                             float* __restrict__ zout_f,
                                             const int* __restrict__ rp,
                                             const int2* __restrict__ cw, int N) {
    int wid  = (blockIdx.x * blockDim.x + threadIdx.x) >> 6;
    int lane = threadIdx.x & 63;
    if (wid >= N) return;

    int e   = __builtin_amdgcn_readfirstlane(rp[wid]);
    int end = __builtin_amdgcn_readfirstlane(rp[wid + 1]);

    float2 hh = *(const float2*)&h[((size_t)wid << 7) + lane * 2];

    float ax = 0.f, ay = 0.f, bx = 0.f, by = 0.f;

    for (; e + 16 <= end; e += 16)
        hop_batch<16>(zin, cw, e, lane, ax, ay, bx, by);
    if (e + 8 <= end) { hop_batch<8>(zin, cw, e, lane, ax, ay, bx, by); e += 8; }
    if (e + 4 <= end) { hop_batch<4>(zin, cw, e, lane, ax, ay, bx, by); e += 4; }
    for (; e < end; ++e) {
        int2 p = cw[e];
        float2 z = unpack_bf16x2(zin[((unsigned)p.x << 6) + lane]);
        float wv = __int_as_float(p.y);
        ax = fmaf(wv, z.x, ax); ay = fmaf(wv, z.y, ay);
    }

    float ox = (ax + bx) + A_ * hh.x;
    float oy = (ay + by) + A_ * hh.y;
    if (OUTF32) {
        float2 o; o.x = ox; o.y = oy;
        *(float2*)&zout_f[((size_t)wid << 7) + lane * 2] = o;
    } else {
        zout_b[((size_t)wid << 6) + lane] = pack_bf16x2(ox, oy);
    }
}

// ---------------- decode: out[j] = dot(z[e0[j]], z[e1[j]]) ----------------

__global__ __launch_bounds__(256) void k_decode(const float* __restrict__ z,
                                                const void* __restrict__ pos,
                                                const void* __restrict__ neg,
                                                float* __restrict__ out, int P, int Q,
                                                const int* __restrict__ flag) {
    int is64 = *flag;
    int t   = blockIdx.x * blockDim.x + threadIdx.x;
    int j   = t >> 4;
    int sub = t & 15;
    if (j >= P + Q) return;
    int a, b;
    if (j < P) { a = idx_at(pos, (size_t)j, is64); b = idx_at(pos, (size_t)P + j, is64); }
    else       { int jj = j - P; a = idx_at(neg, (size_t)jj, is64); b = idx_at(neg, (size_t)Q + jj, is64); }
    const float4* za = (const float4*)&z[(size_t)a * Hd];
    const float4* zb = (const float4*)&z[(size_t)b * Hd];
    float s = 0.f;
#pragma unroll
    for (int q = 0; q < 2; ++q) {
        float4 va = za[q * 16 + sub];
        float4 vb = zb[q * 16 + sub];
        s += va.x * vb.x + va.y * vb.y + va.z * vb.z + va.w * vb.w;
    }
#pragma unroll
    for (int off = 8; off >= 1; off >>= 1) s += __shfl_xor(s, off, 16);
    if (sub == 0) out[j] = s;
}

// ---------------- launch ----------------

extern "C" void kernel_launch(void* const* d_in, const int* in_sizes, int n_in,
                              void* d_out, int out_size, void* d_ws, size_t ws_size,
                              hipStream_t stream) {
    const float* x   = (const float*)d_in[0];
    const void*  ei  = d_in[1];
    const void*  pos = d_in[2];
    const void*  neg = d_in[3];
    const float* W1  = (const float*)d_in[4];
    const float* W2  = (const float*)d_in[5];
    float*       out = (float*)d_out;

    const int N = in_sizes[0] / Fin;
    const int E = in_sizes[1] / 2;
    const int P = in_sizes[2] / 2;
    const int Q = in_sizes[3] / 2;
    const int Etot = E + N;

    char*  ws  = (char*)d_ws;
    size_t off = 0;
    auto carve = [&](size_t bytes) -> void* {
        void* p = ws + off;
        off = (off + bytes + 511) & ~(size_t)511;
        return p;
    };
    float*    h    = (float*)carve((size_t)N * Hd * 4);
    float*    zF   = (float*)carve((size_t)N * Hd * 4);   // fp32 layer output
    unsigned* b0   = (unsigned*)carve((size_t)N * 64 * 4);
    unsigned* b1   = (unsigned*)carve((size_t)N * 64 * 4);
    float*    dinv = (float*)carve((size_t)N * 4);
    int*     cnt    = (int*)carve((size_t)N * 4);
    int*     rp     = (int*)carve((size_t)(N + 1) * 4);
    int*     cursor = (int*)carve((size_t)N * 4);
    int2*    cw     = (int2*)carve((size_t)Etot * 8);
    int      nb     = (N + 255) / 256;
    int*     bsum   = (int*)carve((size_t)nb * 4);
    int*     flag   = (int*)carve(4);
    (void)ws_size;

    const int gN = (N + 255) / 256;
    const int gE = (E + 255) / 256;

    k_detect<<<1, 256, 0, stream>>>((const int*)ei, 4096, flag);
    k_zero_i32<<<gN, 256, 0, stream>>>(cnt, N);
    k_count<<<gE, 256, 0, stream>>>(ei, E, cnt, flag);
    k_dinv<<<gN, 256, 0, stream>>>(cnt, dinv, N);
    k_scan1<<<nb, 256, 0, stream>>>(cnt, rp, bsum, N);
    k_scan2<<<1, 512, 0, stream>>>(bsum, nb);
    k_scan3<<<gN, 256, 0, stream>>>(rp, bsum, cursor, dinv, cw, N, Etot);
    k_place<<<gE, 256, 0, stream>>>(ei, E, rp, cursor, dinv, cw, flag);

    const int gGemm = (N + 63) / 64;
    const int gHop  = (N * 64 + 255) / 256;
    const int n64   = N * 64;
    const int gCvt  = (n64 + 255) / 256;

    unsigned* bufs[2] = {b0, b1};

    // ---- layer 1: h = x @ W1; 10 hops (last writes fp32 zF) ----
    k_gemm<Fin, false><<<gGemm, 256, 0, stream>>>(x, W1, h, N);
    k_cvt<<<gCvt, 256, 0, stream>>>(h, b0, n64);
    for (int k = 0; k < 9; ++k)
        k_hop<false><<<gHop, 256, 0, stream>>>(bufs[k & 1], h, bufs[(k + 1) & 1], nullptr, rp, cw, N);
    k_hop<true><<<gHop, 256, 0, stream>>>(bufs[1], h, nullptr, zF, rp, cw, N);

    // ---- layer 2: h = relu(zF) @ W2; 10 hops (last writes fp32 zF) ----
    k_gemm<Hd, true><<<gGemm, 256, 0, stream>>>(zF, W2, h, N);
    k_cvt<<<gCvt, 256, 0, stream>>>(h, b0, n64);
    for (int k = 0; k < 9; ++k)
        k_hop<false><<<gHop, 256, 0, stream>>>(bufs[k & 1], h, bufs[(k + 1) & 1], nullptr, rp, cw, N);
    k_hop<true><<<gHop, 256, 0, stream>>>(bufs[1], h, nullptr, zF, rp, cw, N);

    // ---- decode ----
    const int gDec = ((P + Q) * 16 + 255) / 256;
    k_decode<<<gDec, 256, 0, stream>>>(zF, pos, neg, out, P, Q, flag);
}

// Round 6
// 1641.376 us; speedup vs baseline: 1.7878x; 1.0750x over previous
//
#include <hip/hip_runtime.h>

// APPNP link-prediction: N=100000, F=256, H=128, E=1.6M, K=10 x 2 layers.
// CSR-by-dst (self-loops folded, 0.9*norm pre-folded), gather-only SpMV hops.
// z stored bf16 (256B rows); teleport term alpha*h pre-scaled to bf16;
// decode gathers bf16 rows. Accumulation stays fp32.

constexpr int Hd = 128;
constexpr int Fin = 256;
constexpr float A_ = 0.1f;
constexpr float OMA = 0.9f;

__device__ __forceinline__ int idx_at(const void* p, size_t i, int is64) {
    if (is64) return (int)((const long long*)p)[i];
    return ((const int*)p)[i];
}

__device__ __forceinline__ unsigned pack_bf16x2(float x, float y) {
    unsigned ux = __float_as_uint(x);
    unsigned uy = __float_as_uint(y);
    ux = (ux + 0x7fffu + ((ux >> 16) & 1u)) >> 16;          // RNE
    uy = (uy + 0x7fffu + ((uy >> 16) & 1u)) & 0xffff0000u;  // RNE, keep high
    return ux | uy;
}

__device__ __forceinline__ float2 unpack_bf16x2(unsigned v) {
    float2 r;
    r.x = __uint_as_float(v << 16);
    r.y = __uint_as_float(v & 0xffff0000u);
    return r;
}

// ---------------- dtype probe ----------------
__global__ void k_detect(const int* __restrict__ p, int npairs, int* __restrict__ flag) {
    __shared__ int any32;
    if (threadIdx.x == 0) any32 = 0;
    __syncthreads();
    for (int i = threadIdx.x; i < npairs; i += blockDim.x)
        if (p[2 * i + 1] != 0) any32 = 1;
    __syncthreads();
    if (threadIdx.x == 0) *flag = any32 ? 0 : 1;   // 1 => int64
}

// ---------------- preprocessing ----------------

__global__ void k_zero_i32(int* __restrict__ p, int n) {
    int i = blockIdx.x * blockDim.x + threadIdx.x;
    if (i < n) p[i] = 0;
}

__global__ void k_count(const void* __restrict__ ei, int E, int* __restrict__ cnt,
                        const int* __restrict__ flag) {
    int is64 = *flag;
    int e = blockIdx.x * blockDim.x + threadIdx.x;
    if (e < E) {
        int d = idx_at(ei, (size_t)E + e, is64);
        atomicAdd(&cnt[d], 1);
    }
}

__global__ void k_dinv(const int* __restrict__ cnt, float* __restrict__ dinv, int N) {
    int i = blockIdx.x * blockDim.x + threadIdx.x;
    if (i < N) dinv[i] = rsqrtf((float)(cnt[i] + 1));
}

__global__ void k_scan1(const int* __restrict__ cnt, int* __restrict__ rp,
                        int* __restrict__ bsum, int N) {
    __shared__ int s[256];
    int t = threadIdx.x;
    int i = blockIdx.x * 256 + t;
    int v = (i < N) ? (cnt[i] + 1) : 0;   // +1 self-loop slot
    s[t] = v;
    __syncthreads();
    for (int off = 1; off < 256; off <<= 1) {
        int add = (t >= off) ? s[t - off] : 0;
        __syncthreads();
        s[t] += add;
        __syncthreads();
    }
    if (i < N) rp[i] = s[t] - v;
    if (t == 255) bsum[blockIdx.x] = s[255];
}

__global__ void k_scan2(int* __restrict__ bsum, int nb) {
    __shared__ int s[512];
    int t = threadIdx.x;
    int v = (t < nb) ? bsum[t] : 0;
    s[t] = v;
    __syncthreads();
    for (int off = 1; off < 512; off <<= 1) {
        int add = (t >= off) ? s[t - off] : 0;
        __syncthreads();
        s[t] += add;
        __syncthreads();
    }
    if (t < nb) bsum[t] = s[t] - v;
}

__global__ void k_scan3(int* __restrict__ rp, const int* __restrict__ bsum,
                        int* __restrict__ cursor, const float* __restrict__ dinv,
                        int2* __restrict__ cw, int N, int Etot) {
    int i = blockIdx.x * blockDim.x + threadIdx.x;
    if (i < N) {
        int r = rp[i] + bsum[i >> 8];
        rp[i] = r;
        cursor[i] = 1;
        float d = dinv[i];
        int2 p;
        p.x = i;
        p.y = __float_as_int(OMA * d * d);
        cw[r] = p;   // self-loop first in each row
    }
    if (i == 0) rp[N] = Etot;
}

__global__ void k_place(const void* __restrict__ ei, int E,
                        const int* __restrict__ rp, int* __restrict__ cursor,
                        const float* __restrict__ dinv,
                        int2* __restrict__ cw, const int* __restrict__ flag) {
    int is64 = *flag;
    int e = blockIdx.x * blockDim.x + threadIdx.x;
    if (e < E) {
        int s = idx_at(ei, (size_t)e, is64);
        int d = idx_at(ei, (size_t)E + e, is64);
        int pos = rp[d] + atomicAdd(&cursor[d], 1);
        int2 p;
        p.x = s;
        p.y = __float_as_int(OMA * dinv[s] * dinv[d]);
        cw[pos] = p;
    }
}

// ---------------- prep: h fp32 -> z0 bf16 and alpha*h bf16 ----------------
__global__ __launch_bounds__(256) void k_prep(const float* __restrict__ in,
                                              unsigned* __restrict__ z0,
                                              unsigned* __restrict__ ah, int n64) {
    int i = blockIdx.x * blockDim.x + threadIdx.x;
    if (i < n64) {
        float2 v = ((const float2*)in)[i];
        z0[i] = pack_bf16x2(v.x, v.y);
        ah[i] = pack_bf16x2(A_ * v.x, A_ * v.y);
    }
}

// ---------------- GEMM: C[N][128] = act(A)[N][KTOT] @ B[KTOT][128] ----------------

template <int KTOT, bool RELU>
__global__ __launch_bounds__(256) void k_gemm(const float* __restrict__ A,
                                              const float* __restrict__ B,
                                              float* __restrict__ C, int N) {
    __shared__ float As[64][36];
    __shared__ float Bs[32][128];
    const int t  = threadIdx.x;
    const int tx = t & 15;
    const int ty = t >> 4;
    const int r0 = blockIdx.x * 64;

    float acc[4][8];
#pragma unroll
    for (int i = 0; i < 4; ++i)
#pragma unroll
        for (int j = 0; j < 8; ++j) acc[i][j] = 0.f;

    for (int k0 = 0; k0 < KTOT; k0 += 32) {
#pragma unroll
        for (int p = 0; p < 2; ++p) {
            int row = p * 32 + (t >> 3);
            int kk  = (t & 7) * 4;
            int gr  = r0 + row;
            float4 v = make_float4(0.f, 0.f, 0.f, 0.f);
            if (gr < N) v = *(const float4*)&A[(size_t)gr * KTOT + k0 + kk];
            if (RELU) {
                v.x = fmaxf(v.x, 0.f); v.y = fmaxf(v.y, 0.f);
                v.z = fmaxf(v.z, 0.f); v.w = fmaxf(v.w, 0.f);
            }
            *(float4*)&As[row][kk] = v;
        }
#pragma unroll
        for (int p = 0; p < 4; ++p) {
            int kr = p * 8 + (t >> 5);
            int c  = (t & 31) * 4;
            *(float4*)&Bs[kr][c] = *(const float4*)&B[(size_t)(k0 + kr) * Hd + c];
        }
        __syncthreads();
#pragma unroll
        for (int kk = 0; kk < 32; ++kk) {
            float a[4];
#pragma unroll
            for (int i = 0; i < 4; ++i) a[i] = As[ty * 4 + i][kk];
            // column-quad split: cols [tx*4, tx*4+4) and [64+tx*4, 64+tx*4+4)
            float4 b0 = *(const float4*)&Bs[kk][tx * 4];
            float4 b1 = *(const float4*)&Bs[kk][64 + tx * 4];
            float b[8] = {b0.x, b0.y, b0.z, b0.w, b1.x, b1.y, b1.z, b1.w};
#pragma unroll
            for (int i = 0; i < 4; ++i)
#pragma unroll
                for (int j = 0; j < 8; ++j) acc[i][j] = fmaf(a[i], b[j], acc[i][j]);
        }
        __syncthreads();
    }
#pragma unroll
    for (int i = 0; i < 4; ++i) {
        int gr = r0 + ty * 4 + i;
        if (gr < N) {
            *(float4*)&C[(size_t)gr * Hd + tx * 4]      = make_float4(acc[i][0], acc[i][1], acc[i][2], acc[i][3]);
            *(float4*)&C[(size_t)gr * Hd + 64 + tx * 4] = make_float4(acc[i][4], acc[i][5], acc[i][6], acc[i][7]);
        }
    }
}

// ---------------- propagation hop (bf16 gather, fp32 accum, bf16 teleport) ----------------

template <int B>
__device__ __forceinline__ void hop_batch(const unsigned* __restrict__ zb,
                                          const int2* __restrict__ cw,
                                          int e, int lane,
                                          float& ax, float& ay,
                                          float& bx, float& by) {
    int2 p[B];
#pragma unroll
    for (int k = 0; k < B; ++k) p[k] = cw[e + k];
    unsigned zv[B];
#pragma unroll
    for (int k = 0; k < B; ++k) zv[k] = zb[((unsigned)p[k].x << 6) + lane];
#pragma unroll
    for (int k = 0; k < B; ++k) {
        float wv = __int_as_float(p[k].y);
        float2 z = unpack_bf16x2(zv[k]);
        if (k & 1) { bx = fmaf(wv, z.x, bx); by = fmaf(wv, z.y, by); }
        else       { ax = fmaf(wv, z.x, ax); ay = fmaf(wv, z.y, ay); }
    }
}

template <bool OUTF32>
__global__ __launch_bounds__(256) void k_hop(const unsigned* __restrict__ zin,
                                             const unsigned* __restrict__ ah,
                                             unsigned* __restrict__ zout_b,
                                             float* __restrict__ zout_f,
                                             const int* __restrict__ rp,
                                             const int2* __restrict__ cw, int N) {
    int wid  = (blockIdx.x * blockDim.x + threadIdx.x) >> 6;
    int lane = threadIdx.x & 63;
    if (wid >= N) return;

    int e   = __builtin_amdgcn_readfirstlane(rp[wid]);
    int end = __builtin_amdgcn_readfirstlane(rp[wid + 1]);

    float2 hh = unpack_bf16x2(ah[((size_t)wid << 6) + lane]);

    float ax = 0.f, ay = 0.f, bx = 0.f, by = 0.f;

    for (; e + 16 <= end; e += 16)
        hop_batch<16>(zin, cw, e, lane, ax, ay, bx, by);
    if (e + 8 <= end) { hop_batch<8>(zin, cw, e, lane, ax, ay, bx, by); e += 8; }
    if (e + 4 <= end) { hop_batch<4>(zin, cw, e, lane, ax, ay, bx, by); e += 4; }
    for (; e < end; ++e) {
        int2 p = cw[e];
        float2 z = unpack_bf16x2(zin[((unsigned)p.x << 6) + lane]);
        float wv = __int_as_float(p.y);
        ax = fmaf(wv, z.x, ax); ay = fmaf(wv, z.y, ay);
    }

    float ox = (ax + bx) + hh.x;
    float oy = (ay + by) + hh.y;
    if (OUTF32) {
        float2 o; o.x = ox; o.y = oy;
        *(float2*)&zout_f[((size_t)wid << 7) + lane * 2] = o;
    } else {
        zout_b[((size_t)wid << 6) + lane] = pack_bf16x2(ox, oy);
    }
}

// ---------------- decode: out[j] = dot(z[e0[j]], z[e1[j]]), z bf16 ----------------

__global__ __launch_bounds__(256) void k_decode(const unsigned* __restrict__ z,
                                                const void* __restrict__ pos,
                                                const void* __restrict__ neg,
                                                float* __restrict__ out, int P, int Q,
                                                const int* __restrict__ flag) {
    int is64 = *flag;
    int t   = blockIdx.x * blockDim.x + threadIdx.x;
    int j   = t >> 4;
    int sub = t & 15;
    if (j >= P + Q) return;
    int a, b;
    if (j < P) { a = idx_at(pos, (size_t)j, is64); b = idx_at(pos, (size_t)P + j, is64); }
    else       { int jj = j - P; a = idx_at(neg, (size_t)jj, is64); b = idx_at(neg, (size_t)Q + jj, is64); }
    const uint4* za = (const uint4*)&z[(size_t)a << 6];
    const uint4* zb = (const uint4*)&z[(size_t)b << 6];
    uint4 va = za[sub];
    uint4 vb = zb[sub];
    float s = 0.f;
    {
        float2 xa, xb;
        xa = unpack_bf16x2(va.x); xb = unpack_bf16x2(vb.x);
        s += xa.x * xb.x + xa.y * xb.y;
        xa = unpack_bf16x2(va.y); xb = unpack_bf16x2(vb.y);
        s += xa.x * xb.x + xa.y * xb.y;
        xa = unpack_bf16x2(va.z); xb = unpack_bf16x2(vb.z);
        s += xa.x * xb.x + xa.y * xb.y;
        xa = unpack_bf16x2(va.w); xb = unpack_bf16x2(vb.w);
        s += xa.x * xb.x + xa.y * xb.y;
    }
#pragma unroll
    for (int off = 8; off >= 1; off >>= 1) s += __shfl_xor(s, off, 16);
    if (sub == 0) out[j] = s;
}

// ---------------- launch ----------------

extern "C" void kernel_launch(void* const* d_in, const int* in_sizes, int n_in,
                              void* d_out, int out_size, void* d_ws, size_t ws_size,
                              hipStream_t stream) {
    const float* x   = (const float*)d_in[0];
    const void*  ei  = d_in[1];
    const void*  pos = d_in[2];
    const void*  neg = d_in[3];
    const float* W1  = (const float*)d_in[4];
    const float* W2  = (const float*)d_in[5];
    float*       out = (float*)d_out;

    const int N = in_sizes[0] / Fin;
    const int E = in_sizes[1] / 2;
    const int P = in_sizes[2] / 2;
    const int Q = in_sizes[3] / 2;
    const int Etot = E + N;

    char*  ws  = (char*)d_ws;
    size_t off = 0;
    auto carve = [&](size_t bytes) -> void* {
        void* p = ws + off;
        off = (off + bytes + 511) & ~(size_t)511;
        return p;
    };
    float*    h    = (float*)carve((size_t)N * Hd * 4);
    float*    zF   = (float*)carve((size_t)N * Hd * 4);   // fp32 layer-1 output
    unsigned* b0   = (unsigned*)carve((size_t)N * 64 * 4);
    unsigned* b1   = (unsigned*)carve((size_t)N * 64 * 4);
    unsigned* ah   = (unsigned*)carve((size_t)N * 64 * 4);
    float*    dinv = (float*)carve((size_t)N * 4);
    int*     cnt    = (int*)carve((size_t)N * 4);
    int*     rp     = (int*)carve((size_t)(N + 1) * 4);
    int*     cursor = (int*)carve((size_t)N * 4);
    int2*    cw     = (int2*)carve((size_t)Etot * 8);
    int      nb     = (N + 255) / 256;
    int*     bsum   = (int*)carve((size_t)nb * 4);
    int*     flag   = (int*)carve(4);
    (void)ws_size;

    const int gN = (N + 255) / 256;
    const int gE = (E + 255) / 256;

    k_detect<<<1, 256, 0, stream>>>((const int*)ei, 4096, flag);
    k_zero_i32<<<gN, 256, 0, stream>>>(cnt, N);
    k_count<<<gE, 256, 0, stream>>>(ei, E, cnt, flag);
    k_dinv<<<gN, 256, 0, stream>>>(cnt, dinv, N);
    k_scan1<<<nb, 256, 0, stream>>>(cnt, rp, bsum, N);
    k_scan2<<<1, 512, 0, stream>>>(bsum, nb);
    k_scan3<<<gN, 256, 0, stream>>>(rp, bsum, cursor, dinv, cw, N, Etot);
    k_place<<<gE, 256, 0, stream>>>(ei, E, rp, cursor, dinv, cw, flag);

    const int gGemm = (N + 63) / 64;
    const int gHop  = (N * 64 + 255) / 256;
    const int n64   = N * 64;
    const int gCvt  = (n64 + 255) / 256;

    unsigned* bufs[2] = {b0, b1};

    // ---- layer 1: h = x @ W1; 10 hops (last writes fp32 zF) ----
    k_gemm<Fin, false><<<gGemm, 256, 0, stream>>>(x, W1, h, N);
    k_prep<<<gCvt, 256, 0, stream>>>(h, b0, ah, n64);
    for (int k = 0; k < 9; ++k)
        k_hop<false><<<gHop, 256, 0, stream>>>(bufs[k & 1], ah, bufs[(k + 1) & 1], nullptr, rp, cw, N);
    k_hop<true><<<gHop, 256, 0, stream>>>(bufs[1], ah, nullptr, zF, rp, cw, N);

    // ---- layer 2: h = relu(zF) @ W2; 10 hops (final stays bf16 in b0) ----
    k_gemm<Hd, true><<<gGemm, 256, 0, stream>>>(zF, W2, h, N);
    k_prep<<<gCvt, 256, 0, stream>>>(h, b0, ah, n64);
    for (int k = 0; k < 10; ++k)
        k_hop<false><<<gHop, 256, 0, stream>>>(bufs[k & 1], ah, bufs[(k + 1) & 1], nullptr, rp, cw, N);
    // 10 hops: k=9 writes bufs[0] = b0

    // ---- decode (bf16 z) ----
    const int gDec = ((P + Q) * 16 + 255) / 256;
    k_decode<<<gDec, 256, 0, stream>>>(b0, pos, neg, out, P, Q, flag);
}

// Round 8
// 1202.771 us; speedup vs baseline: 2.4397x; 1.3647x over previous
//
#include <hip/hip_runtime.h>

// APPNP link-prediction: N=100000, F=256, H=128, E=1.6M, K=10 x 2 layers.
// CSR-by-dst (self-loops folded, 0.9*norm pre-folded), gather-only SpMV hops.
// Intermediate z stored fp8 e4m3 (128B rows = 1 cache line per gather);
// penultimate hop writes bf16, final hop writes f32/bf16 -> error stays ~bf16.
// GEMM epilogue fuses z0-fp8 + alpha*h-bf16 emission (no fp32 h buffer).

constexpr int Hd = 128;
constexpr int Fin = 256;
constexpr float A_ = 0.1f;
constexpr float OMA = 0.9f;

typedef float vf2 __attribute__((ext_vector_type(2)));

__device__ __forceinline__ int idx_at(const void* p, size_t i, int is64) {
    if (is64) return (int)((const long long*)p)[i];
    return ((const int*)p)[i];
}

__device__ __forceinline__ unsigned pack_bf16x2(float x, float y) {
    unsigned ux = __float_as_uint(x);
    unsigned uy = __float_as_uint(y);
    ux = (ux + 0x7fffu + ((ux >> 16) & 1u)) >> 16;          // RNE
    uy = (uy + 0x7fffu + ((uy >> 16) & 1u)) & 0xffff0000u;  // RNE, keep high
    return ux | uy;
}

__device__ __forceinline__ float2 unpack_bf16x2(unsigned v) {
    float2 r;
    r.x = __uint_as_float(v << 16);
    r.y = __uint_as_float(v & 0xffff0000u);
    return r;
}

__device__ __forceinline__ unsigned short pack_fp8x2(float x, float y) {
    int v = __builtin_amdgcn_cvt_pk_fp8_f32(x, y, 0, false);   // low word
    return (unsigned short)(unsigned)v;
}

__device__ __forceinline__ float2 unpack_fp8x2(unsigned short v) {
    vf2 r = __builtin_amdgcn_cvt_pk_f32_fp8((int)(unsigned)v, false);
    float2 o;
    o.x = r[0];
    o.y = r[1];
    return o;
}

// ---------------- dtype probe ----------------
__global__ void k_detect(const int* __restrict__ p, int npairs, int* __restrict__ flag) {
    __shared__ int any32;
    if (threadIdx.x == 0) any32 = 0;
    __syncthreads();
    for (int i = threadIdx.x; i < npairs; i += blockDim.x)
        if (p[2 * i + 1] != 0) any32 = 1;
    __syncthreads();
    if (threadIdx.x == 0) *flag = any32 ? 0 : 1;   // 1 => int64
}

// ---------------- preprocessing ----------------

__global__ void k_zero_i32(int* __restrict__ p, int n) {
    int i = blockIdx.x * blockDim.x + threadIdx.x;
    if (i < n) p[i] = 0;
}

__global__ void k_count(const void* __restrict__ ei, int E, int* __restrict__ cnt,
                        const int* __restrict__ flag) {
    int is64 = *flag;
    int e = blockIdx.x * blockDim.x + threadIdx.x;
    if (e < E) {
        int d = idx_at(ei, (size_t)E + e, is64);
        atomicAdd(&cnt[d], 1);
    }
}

__global__ void k_dinv(const int* __restrict__ cnt, float* __restrict__ dinv, int N) {
    int i = blockIdx.x * blockDim.x + threadIdx.x;
    if (i < N) dinv[i] = rsqrtf((float)(cnt[i] + 1));
}

__global__ void k_scan1(const int* __restrict__ cnt, int* __restrict__ rp,
                        int* __restrict__ bsum, int N) {
    __shared__ int s[256];
    int t = threadIdx.x;
    int i = blockIdx.x * 256 + t;
    int v = (i < N) ? (cnt[i] + 1) : 0;   // +1 self-loop slot
    s[t] = v;
    __syncthreads();
    for (int off = 1; off < 256; off <<= 1) {
        int add = (t >= off) ? s[t - off] : 0;
        __syncthreads();
        s[t] += add;
        __syncthreads();
    }
    if (i < N) rp[i] = s[t] - v;
    if (t == 255) bsum[blockIdx.x] = s[255];
}

__global__ void k_scan2(int* __restrict__ bsum, int nb) {
    __shared__ int s[512];
    int t = threadIdx.x;
    int v = (t < nb) ? bsum[t] : 0;
    s[t] = v;
    __syncthreads();
    for (int off = 1; off < 512; off <<= 1) {
        int add = (t >= off) ? s[t - off] : 0;
        __syncthreads();
        s[t] += add;
        __syncthreads();
    }
    if (t < nb) bsum[t] = s[t] - v;
}

__global__ void k_scan3(int* __restrict__ rp, const int* __restrict__ bsum,
                        int* __restrict__ cursor, const float* __restrict__ dinv,
                        int2* __restrict__ cw, int N, int Etot) {
    int i = blockIdx.x * blockDim.x + threadIdx.x;
    if (i < N) {
        int r = rp[i] + bsum[i >> 8];
        rp[i] = r;
        cursor[i] = 1;
        float d = dinv[i];
        int2 p;
        p.x = i;
        p.y = __float_as_int(OMA * d * d);
        cw[r] = p;   // self-loop first in each row
    }
    if (i == 0) rp[N] = Etot;
}

__global__ void k_place(const void* __restrict__ ei, int E,
                        const int* __restrict__ rp, int* __restrict__ cursor,
                        const float* __restrict__ dinv,
                        int2* __restrict__ cw, const int* __restrict__ flag) {
    int is64 = *flag;
    int e = blockIdx.x * blockDim.x + threadIdx.x;
    if (e < E) {
        int s = idx_at(ei, (size_t)e, is64);
        int d = idx_at(ei, (size_t)E + e, is64);
        int pos = rp[d] + atomicAdd(&cursor[d], 1);
        int2 p;
        p.x = s;
        p.y = __float_as_int(OMA * dinv[s] * dinv[d]);
        cw[pos] = p;
    }
}

// ---------------- GEMM: emits z0 fp8 + alpha*h bf16 (no fp32 C) ----------------

template <int KTOT, bool RELU>
__global__ __launch_bounds__(256) void k_gemm(const float* __restrict__ A,
                                              const float* __restrict__ B,
                                              unsigned short* __restrict__ z0,
                                              unsigned* __restrict__ ah, int N) {
    __shared__ float As[64][36];
    __shared__ float Bs[32][128];
    const int t  = threadIdx.x;
    const int tx = t & 15;
    const int ty = t >> 4;
    const int r0 = blockIdx.x * 64;

    float acc[4][8];
#pragma unroll
    for (int i = 0; i < 4; ++i)
#pragma unroll
        for (int j = 0; j < 8; ++j) acc[i][j] = 0.f;

    for (int k0 = 0; k0 < KTOT; k0 += 32) {
#pragma unroll
        for (int p = 0; p < 2; ++p) {
            int row = p * 32 + (t >> 3);
            int kk  = (t & 7) * 4;
            int gr  = r0 + row;
            float4 v = make_float4(0.f, 0.f, 0.f, 0.f);
            if (gr < N) v = *(const float4*)&A[(size_t)gr * KTOT + k0 + kk];
            if (RELU) {
                v.x = fmaxf(v.x, 0.f); v.y = fmaxf(v.y, 0.f);
                v.z = fmaxf(v.z, 0.f); v.w = fmaxf(v.w, 0.f);
            }
            *(float4*)&As[row][kk] = v;
        }
#pragma unroll
        for (int p = 0; p < 4; ++p) {
            int kr = p * 8 + (t >> 5);
            int c  = (t & 31) * 4;
            *(float4*)&Bs[kr][c] = *(const float4*)&B[(size_t)(k0 + kr) * Hd + c];
        }
        __syncthreads();
#pragma unroll
        for (int kk = 0; kk < 32; ++kk) {
            float a[4];
#pragma unroll
            for (int i = 0; i < 4; ++i) a[i] = As[ty * 4 + i][kk];
            float4 b0 = *(const float4*)&Bs[kk][tx * 4];
            float4 b1 = *(const float4*)&Bs[kk][64 + tx * 4];
            float b[8] = {b0.x, b0.y, b0.z, b0.w, b1.x, b1.y, b1.z, b1.w};
#pragma unroll
            for (int i = 0; i < 4; ++i)
#pragma unroll
                for (int j = 0; j < 8; ++j) acc[i][j] = fmaf(a[i], b[j], acc[i][j]);
        }
        __syncthreads();
    }
    // epilogue: cols [tx*4, tx*4+4) and [64+tx*4, ...)
#pragma unroll
    for (int i = 0; i < 4; ++i) {
        int gr = r0 + ty * 4 + i;
        if (gr < N) {
            ushort2 f0, f1;
            f0.x = pack_fp8x2(acc[i][0], acc[i][1]);
            f0.y = pack_fp8x2(acc[i][2], acc[i][3]);
            f1.x = pack_fp8x2(acc[i][4], acc[i][5]);
            f1.y = pack_fp8x2(acc[i][6], acc[i][7]);
            *(ushort2*)&z0[((size_t)gr << 6) + tx * 2]      = f0;
            *(ushort2*)&z0[((size_t)gr << 6) + 32 + tx * 2] = f1;
            uint2 a0, a1;
            a0.x = pack_bf16x2(A_ * acc[i][0], A_ * acc[i][1]);
            a0.y = pack_bf16x2(A_ * acc[i][2], A_ * acc[i][3]);
            a1.x = pack_bf16x2(A_ * acc[i][4], A_ * acc[i][5]);
            a1.y = pack_bf16x2(A_ * acc[i][6], A_ * acc[i][7]);
            *(uint2*)&ah[((size_t)gr << 6) + tx * 2]      = a0;
            *(uint2*)&ah[((size_t)gr << 6) + 32 + tx * 2] = a1;
        }
    }
}

// ---------------- propagation hop ----------------
// IN8: 1 = fp8 input rows (128B), 0 = bf16 input rows (256B)
// OUTM: 0 = fp8, 1 = bf16, 2 = f32

template <int B, int IN8>
__device__ __forceinline__ void hop_batch(const void* __restrict__ zb,
                                          const int2* __restrict__ cw,
                                          int e, int lane,
                                          float& ax, float& ay,
                                          float& bx, float& by) {
    int2 p[B];
#pragma unroll
    for (int k = 0; k < B; ++k) p[k] = cw[e + k];
    unsigned zv[B];
#pragma unroll
    for (int k = 0; k < B; ++k) {
        if (IN8) zv[k] = ((const unsigned short*)zb)[((unsigned)p[k].x << 6) + lane];
        else     zv[k] = ((const unsigned*)zb)[((unsigned)p[k].x << 6) + lane];
    }
#pragma unroll
    for (int k = 0; k < B; ++k) {
        float wv = __int_as_float(p[k].y);
        float2 z = IN8 ? unpack_fp8x2((unsigned short)zv[k]) : unpack_bf16x2(zv[k]);
        if (k & 1) { bx = fmaf(wv, z.x, bx); by = fmaf(wv, z.y, by); }
        else       { ax = fmaf(wv, z.x, ax); ay = fmaf(wv, z.y, ay); }
    }
}

template <int IN8, int OUTM>
__global__ __launch_bounds__(256) void k_hop(const void* __restrict__ zin,
                                             const unsigned* __restrict__ ah,
                                             void* __restrict__ zout,
                                             const int* __restrict__ rp,
                                             const int2* __restrict__ cw, int N) {
    int wid  = (blockIdx.x * blockDim.x + threadIdx.x) >> 6;
    int lane = threadIdx.x & 63;
    if (wid >= N) return;

    int e   = __builtin_amdgcn_readfirstlane(rp[wid]);
    int end = __builtin_amdgcn_readfirstlane(rp[wid + 1]);

    float2 hh = unpack_bf16x2(ah[((size_t)wid << 6) + lane]);

    float ax = 0.f, ay = 0.f, bx = 0.f, by = 0.f;

    for (; e + 16 <= end; e += 16)
        hop_batch<16, IN8>(zin, cw, e, lane, ax, ay, bx, by);
    if (e + 8 <= end) { hop_batch<8, IN8>(zin, cw, e, lane, ax, ay, bx, by); e += 8; }
    if (e + 4 <= end) { hop_batch<4, IN8>(zin, cw, e, lane, ax, ay, bx, by); e += 4; }
    for (; e < end; ++e) {
        int2 p = cw[e];
        unsigned zv;
        if (IN8) zv = ((const unsigned short*)zin)[((unsigned)p.x << 6) + lane];
        else     zv = ((const unsigned*)zin)[((unsigned)p.x << 6) + lane];
        float2 z = IN8 ? unpack_fp8x2((unsigned short)zv) : unpack_bf16x2(zv);
        float wv = __int_as_float(p.y);
        ax = fmaf(wv, z.x, ax); ay = fmaf(wv, z.y, ay);
    }

    float ox = (ax + bx) + hh.x;
    float oy = (ay + by) + hh.y;
    if (OUTM == 0) {
        ((unsigned short*)zout)[((size_t)wid << 6) + lane] = pack_fp8x2(ox, oy);
    } else if (OUTM == 1) {
        ((unsigned*)zout)[((size_t)wid << 6) + lane] = pack_bf16x2(ox, oy);
    } else {
        float2 o; o.x = ox; o.y = oy;
        *(float2*)&((float*)zout)[((size_t)wid << 7) + lane * 2] = o;
    }
}

// ---------------- decode: out[j] = dot(z[e0[j]], z[e1[j]]), z bf16 ----------------

__global__ __launch_bounds__(256) void k_decode(const unsigned* __restrict__ z,
                                                const void* __restrict__ pos,
                                                const void* __restrict__ neg,
                                                float* __restrict__ out, int P, int Q,
                                                const int* __restrict__ flag) {
    int is64 = *flag;
    int t   = blockIdx.x * blockDim.x + threadIdx.x;
    int j   = t >> 4;
    int sub = t & 15;
    if (j >= P + Q) return;
    int a, b;
    if (j < P) { a = idx_at(pos, (size_t)j, is64); b = idx_at(pos, (size_t)P + j, is64); }
    else       { int jj = j - P; a = idx_at(neg, (size_t)jj, is64); b = idx_at(neg, (size_t)Q + jj, is64); }
    const uint4* za = (const uint4*)&z[(size_t)a << 6];
    const uint4* zb = (const uint4*)&z[(size_t)b << 6];
    uint4 va = za[sub];
    uint4 vb = zb[sub];
    float s = 0.f;
    {
        float2 xa, xb;
        xa = unpack_bf16x2(va.x); xb = unpack_bf16x2(vb.x);
        s += xa.x * xb.x + xa.y * xb.y;
        xa = unpack_bf16x2(va.y); xb = unpack_bf16x2(vb.y);
        s += xa.x * xb.x + xa.y * xb.y;
        xa = unpack_bf16x2(va.z); xb = unpack_bf16x2(vb.z);
        s += xa.x * xb.x + xa.y * xb.y;
        xa = unpack_bf16x2(va.w); xb = unpack_bf16x2(vb.w);
        s += xa.x * xb.x + xa.y * xb.y;
    }
#pragma unroll
    for (int off = 8; off >= 1; off >>= 1) s += __shfl_xor(s, off, 16);
    if (sub == 0) out[j] = s;
}

// ---------------- launch ----------------

extern "C" void kernel_launch(void* const* d_in, const int* in_sizes, int n_in,
                              void* d_out, int out_size, void* d_ws, size_t ws_size,
                              hipStream_t stream) {
    const float* x   = (const float*)d_in[0];
    const void*  ei  = d_in[1];
    const void*  pos = d_in[2];
    const void*  neg = d_in[3];
    const float* W1  = (const float*)d_in[4];
    const float* W2  = (const float*)d_in[5];
    float*       out = (float*)d_out;

    const int N = in_sizes[0] / Fin;
    const int E = in_sizes[1] / 2;
    const int P = in_sizes[2] / 2;
    const int Q = in_sizes[3] / 2;
    const int Etot = E + N;

    char*  ws  = (char*)d_ws;
    size_t off = 0;
    auto carve = [&](size_t bytes) -> void* {
        void* p = ws + off;
        off = (off + bytes + 511) & ~(size_t)511;
        return p;
    };
    float*          zF   = (float*)carve((size_t)N * Hd * 4);       // fp32 layer-1 out
    unsigned short* f0   = (unsigned short*)carve((size_t)N * 64 * 2);
    unsigned short* f1   = (unsigned short*)carve((size_t)N * 64 * 2);
    unsigned*       zBF  = (unsigned*)carve((size_t)N * 64 * 4);    // bf16 penult
    unsigned*       zB2  = (unsigned*)carve((size_t)N * 64 * 4);    // bf16 final (decode)
    unsigned*       ah   = (unsigned*)carve((size_t)N * 64 * 4);
    float*          dinv = (float*)carve((size_t)N * 4);
    int*     cnt    = (int*)carve((size_t)N * 4);
    int*     rp     = (int*)carve((size_t)(N + 1) * 4);
    int*     cursor = (int*)carve((size_t)N * 4);
    int2*    cw     = (int2*)carve((size_t)Etot * 8);
    int      nb     = (N + 255) / 256;
    int*     bsum   = (int*)carve((size_t)nb * 4);
    int*     flag   = (int*)carve(4);
    (void)ws_size;

    const int gN = (N + 255) / 256;
    const int gE = (E + 255) / 256;

    k_detect<<<1, 256, 0, stream>>>((const int*)ei, 4096, flag);
    k_zero_i32<<<gN, 256, 0, stream>>>(cnt, N);
    k_count<<<gE, 256, 0, stream>>>(ei, E, cnt, flag);
    k_dinv<<<gN, 256, 0, stream>>>(cnt, dinv, N);
    k_scan1<<<nb, 256, 0, stream>>>(cnt, rp, bsum, N);
    k_scan2<<<1, 512, 0, stream>>>(bsum, nb);
    k_scan3<<<gN, 256, 0, stream>>>(rp, bsum, cursor, dinv, cw, N, Etot);
    k_place<<<gE, 256, 0, stream>>>(ei, E, rp, cursor, dinv, cw, flag);

    const int gGemm = (N + 63) / 64;
    const int gHop  = (N * 64 + 255) / 256;

    unsigned short* fb[2] = {f0, f1};

    // ---- layer 1: GEMM emits z0 fp8 + ah bf16; hops 1-8 fp8, 9 ->bf16, 10 ->f32 ----
    k_gemm<Fin, false><<<gGemm, 256, 0, stream>>>(x, W1, f0, ah, N);
    for (int k = 0; k < 8; ++k)
        k_hop<1, 0><<<gHop, 256, 0, stream>>>(fb[k & 1], ah, fb[(k + 1) & 1], rp, cw, N);
    k_hop<1, 1><<<gHop, 256, 0, stream>>>(f0, ah, zBF, rp, cw, N);
    k_hop<0, 2><<<gHop, 256, 0, stream>>>(zBF, ah, zF, rp, cw, N);

    // ---- layer 2: GEMM(relu) emits z0 fp8 + ah bf16; hops; final -> bf16 zB2 ----
    k_gemm<Hd, true><<<gGemm, 256, 0, stream>>>(zF, W2, f0, ah, N);
    for (int k = 0; k < 8; ++k)
        k_hop<1, 0><<<gHop, 256, 0, stream>>>(fb[k & 1], ah, fb[(k + 1) & 1], rp, cw, N);
    k_hop<1, 1><<<gHop, 256, 0, stream>>>(f0, ah, zBF, rp, cw, N);
    k_hop<0, 1><<<gHop, 256, 0, stream>>>(zBF, ah, zB2, rp, cw, N);

    // ---- decode (bf16 z) ----
    const int gDec = ((P + Q) * 16 + 255) / 256;
    k_decode<<<gDec, 256, 0, stream>>>(zB2, pos, neg, out, P, Q, flag);
}

// Round 9
// 1088.566 us; speedup vs baseline: 2.6957x; 1.1049x over previous
//
#include <hip/hip_runtime.h>

// APPNP link-prediction: N=100000, F=256, H=128, E=1.6M, K=10 x 2 layers.
// CSR-by-dst (self-loops folded, 0.9*norm pre-folded), gather-only SpMV hops.
// z stored fp8 e4m3 during hops (128B rows); penult hop bf16; L1 final hop
// emits relu'd bf16 for the L2 MFMA GEMM. GEMMs use v_mfma_f32_16x16x32_bf16.

constexpr int Hd = 128;
constexpr int Fin = 256;
constexpr float A_ = 0.1f;
constexpr float OMA = 0.9f;

typedef float vf2 __attribute__((ext_vector_type(2)));
typedef __bf16 bf16x8 __attribute__((ext_vector_type(8)));
typedef float f32x4 __attribute__((ext_vector_type(4)));

__device__ __forceinline__ int idx_at(const void* p, size_t i, int is64) {
    if (is64) return (int)((const long long*)p)[i];
    return ((const int*)p)[i];
}

__device__ __forceinline__ unsigned short bf16_of(float x) {
    unsigned u = __float_as_uint(x);
    return (unsigned short)((u + 0x7fffu + ((u >> 16) & 1u)) >> 16);
}

__device__ __forceinline__ unsigned pack_bf16x2(float x, float y) {
    unsigned ux = __float_as_uint(x);
    unsigned uy = __float_as_uint(y);
    ux = (ux + 0x7fffu + ((ux >> 16) & 1u)) >> 16;          // RNE
    uy = (uy + 0x7fffu + ((uy >> 16) & 1u)) & 0xffff0000u;  // RNE, keep high
    return ux | uy;
}

__device__ __forceinline__ float2 unpack_bf16x2(unsigned v) {
    float2 r;
    r.x = __uint_as_float(v << 16);
    r.y = __uint_as_float(v & 0xffff0000u);
    return r;
}

__device__ __forceinline__ unsigned short pack_fp8x2(float x, float y) {
    int v = __builtin_amdgcn_cvt_pk_fp8_f32(x, y, 0, false);   // low word
    return (unsigned short)(unsigned)v;
}

__device__ __forceinline__ float2 unpack_fp8x2(unsigned short v) {
    vf2 r = __builtin_amdgcn_cvt_pk_f32_fp8((int)(unsigned)v, false);
    float2 o;
    o.x = r[0];
    o.y = r[1];
    return o;
}

// ---------------- dtype probe ----------------
__global__ void k_detect(const int* __restrict__ p, int npairs, int* __restrict__ flag) {
    __shared__ int any32;
    if (threadIdx.x == 0) any32 = 0;
    __syncthreads();
    for (int i = threadIdx.x; i < npairs; i += blockDim.x)
        if (p[2 * i + 1] != 0) any32 = 1;
    __syncthreads();
    if (threadIdx.x == 0) *flag = any32 ? 0 : 1;   // 1 => int64
}

// ---------------- preprocessing ----------------

__global__ void k_zero_i32(int* __restrict__ p, int n) {
    int i = blockIdx.x * blockDim.x + threadIdx.x;
    if (i < n) p[i] = 0;
}

__global__ void k_count(const void* __restrict__ ei, int E, int* __restrict__ cnt,
                        const int* __restrict__ flag) {
    int is64 = *flag;
    int e = blockIdx.x * blockDim.x + threadIdx.x;
    if (e < E) {
        int d = idx_at(ei, (size_t)E + e, is64);
        atomicAdd(&cnt[d], 1);
    }
}

__global__ void k_dinv(const int* __restrict__ cnt, float* __restrict__ dinv, int N) {
    int i = blockIdx.x * blockDim.x + threadIdx.x;
    if (i < N) dinv[i] = rsqrtf((float)(cnt[i] + 1));
}

__global__ void k_scan1(const int* __restrict__ cnt, int* __restrict__ rp,
                        int* __restrict__ bsum, int N) {
    __shared__ int s[256];
    int t = threadIdx.x;
    int i = blockIdx.x * 256 + t;
    int v = (i < N) ? (cnt[i] + 1) : 0;   // +1 self-loop slot
    s[t] = v;
    __syncthreads();
    for (int off = 1; off < 256; off <<= 1) {
        int add = (t >= off) ? s[t - off] : 0;
        __syncthreads();
        s[t] += add;
        __syncthreads();
    }
    if (i < N) rp[i] = s[t] - v;
    if (t == 255) bsum[blockIdx.x] = s[255];
}

__global__ void k_scan2(int* __restrict__ bsum, int nb) {
    __shared__ int s[512];
    int t = threadIdx.x;
    int v = (t < nb) ? bsum[t] : 0;
    s[t] = v;
    __syncthreads();
    for (int off = 1; off < 512; off <<= 1) {
        int add = (t >= off) ? s[t - off] : 0;
        __syncthreads();
        s[t] += add;
        __syncthreads();
    }
    if (t < nb) bsum[t] = s[t] - v;
}

__global__ void k_scan3(int* __restrict__ rp, const int* __restrict__ bsum,
                        int* __restrict__ cursor, const float* __restrict__ dinv,
                        int2* __restrict__ cw, int N, int Etot) {
    int i = blockIdx.x * blockDim.x + threadIdx.x;
    if (i < N) {
        int r = rp[i] + bsum[i >> 8];
        rp[i] = r;
        cursor[i] = 1;
        float d = dinv[i];
        int2 p;
        p.x = i;
        p.y = __float_as_int(OMA * d * d);
        cw[r] = p;   // self-loop first in each row
    }
    if (i == 0) rp[N] = Etot;
}

__global__ void k_place(const void* __restrict__ ei, int E,
                        const int* __restrict__ rp, int* __restrict__ cursor,
                        const float* __restrict__ dinv,
                        int2* __restrict__ cw, const int* __restrict__ flag) {
    int is64 = *flag;
    int e = blockIdx.x * blockDim.x + threadIdx.x;
    if (e < E) {
        int s = idx_at(ei, (size_t)e, is64);
        int d = idx_at(ei, (size_t)E + e, is64);
        int pos = rp[d] + atomicAdd(&cursor[d], 1);
        int2 p;
        p.x = s;
        p.y = __float_as_int(OMA * dinv[s] * dinv[d]);
        cw[pos] = p;
    }
}

// ---------------- W transpose+cvt: Wt[c][k] = bf16(W[k][c]), W is [K][128] ----------------
__global__ void k_wt(const float* __restrict__ W, unsigned short* __restrict__ Wt, int K) {
    int i = blockIdx.x * blockDim.x + threadIdx.x;
    if (i < K * 128) {
        int k = i >> 7, c = i & 127;
        Wt[c * K + k] = bf16_of(W[i]);
    }
}

// ---------------- MFMA GEMM: z0 fp8 + alpha*h bf16 from A[N][KTOT] @ W[KTOT][128] ----------------
// AF32: A is fp32 (converted in staging); else A is bf16 (ushort rows).
// Tile 64x128, 4 waves (2 row-halves x 2 col-halves), K-step 32.

template <int KTOT, bool AF32>
__global__ __launch_bounds__(256) void k_gemm_mfma(const void* __restrict__ Ap,
                                                   const unsigned short* __restrict__ Wt,
                                                   unsigned short* __restrict__ z0,
                                                   unsigned* __restrict__ ah, int N) {
    __shared__ __align__(16) char smem[64 * 132 * 4];   // 33792 B; union staging/epilogue
    unsigned short (*As)[40] = (unsigned short(*)[40])smem;            // 64 x 32 (+8 pad)
    unsigned short (*Bs)[40] = (unsigned short(*)[40])(smem + 5120);   // 128 x 32 (+8 pad), [col][k]
    float (*Cs)[132] = (float(*)[132])smem;

    const int t    = threadIdx.x;
    const int lane = t & 63;
    const int w    = t >> 6;
    const int wr   = w >> 1;       // 0,1 -> row-half
    const int wc   = w & 1;        // 0,1 -> col-half
    const int r0   = blockIdx.x * 64;

    f32x4 acc[2][4];
#pragma unroll
    for (int i = 0; i < 2; ++i)
#pragma unroll
        for (int j = 0; j < 4; ++j)
#pragma unroll
            for (int q = 0; q < 4; ++q) acc[i][j][q] = 0.f;

    const int arow = t >> 2;          // staging: 0..63
    const int akc  = (t & 3) * 8;     // 0,8,16,24
    const int bcol = t >> 1;          // 0..127
    const int bkc  = (t & 1) * 16;    // 0,16

    for (int k0 = 0; k0 < KTOT; k0 += 32) {
        // ---- stage A (64x32) ----
        {
            int gr = r0 + arow;
            if (AF32) {
                uint4 s = make_uint4(0, 0, 0, 0);
                if (gr < N) {
                    const float* a = (const float*)Ap + (size_t)gr * KTOT + k0 + akc;
                    float4 v0 = *(const float4*)a;
                    float4 v1 = *(const float4*)(a + 4);
                    s.x = pack_bf16x2(v0.x, v0.y);
                    s.y = pack_bf16x2(v0.z, v0.w);
                    s.z = pack_bf16x2(v1.x, v1.y);
                    s.w = pack_bf16x2(v1.z, v1.w);
                }
                *(uint4*)&As[arow][akc] = s;
            } else {
                uint4 s = make_uint4(0, 0, 0, 0);
                if (gr < N) s = *(const uint4*)((const unsigned short*)Ap + (size_t)gr * KTOT + k0 + akc);
                *(uint4*)&As[arow][akc] = s;
            }
        }
        // ---- stage B: Bs[col][k] from Wt[col][KTOT] ----
        {
            const unsigned short* wsrc = Wt + (size_t)bcol * KTOT + k0 + bkc;
            *(uint4*)&Bs[bcol][bkc]     = *(const uint4*)wsrc;
            *(uint4*)&Bs[bcol][bkc + 8] = *(const uint4*)(wsrc + 8);
        }
        __syncthreads();
        // ---- fragments + MFMA ----
        {
            const int kblk = (lane >> 4) * 8;
            const int l15  = lane & 15;
            bf16x8 af[2], bfr[4];
#pragma unroll
            for (int i = 0; i < 2; ++i)
                af[i] = *(const bf16x8*)&As[wr * 32 + i * 16 + l15][kblk];
#pragma unroll
            for (int j = 0; j < 4; ++j)
                bfr[j] = *(const bf16x8*)&Bs[wc * 64 + j * 16 + l15][kblk];
#pragma unroll
            for (int i = 0; i < 2; ++i)
#pragma unroll
                for (int j = 0; j < 4; ++j)
                    acc[i][j] = __builtin_amdgcn_mfma_f32_16x16x32_bf16(af[i], bfr[j], acc[i][j], 0, 0, 0);
        }
        __syncthreads();
    }

    // ---- epilogue: acc -> Cs (f32) -> pack fp8 z0 + bf16 ah ----
    {
        const int l15 = lane & 15;
        const int rq  = (lane >> 4) * 4;
#pragma unroll
        for (int i = 0; i < 2; ++i)
#pragma unroll
            for (int j = 0; j < 4; ++j)
#pragma unroll
                for (int q = 0; q < 4; ++q)
                    Cs[wr * 32 + i * 16 + rq + q][wc * 64 + j * 16 + l15] = acc[i][j][q];
    }
    __syncthreads();
    {
        const int row = t >> 2;
        const int cb  = (t & 3) * 32;
        const int gr  = r0 + row;
        if (gr < N) {
            float c[32];
#pragma unroll
            for (int m = 0; m < 8; ++m) {
                float4 v = *(const float4*)&Cs[row][cb + m * 4];
                c[m * 4 + 0] = v.x; c[m * 4 + 1] = v.y; c[m * 4 + 2] = v.z; c[m * 4 + 3] = v.w;
            }
            unsigned pk[8];
#pragma unroll
            for (int m = 0; m < 8; ++m) {
                unsigned lo = (unsigned)pack_fp8x2(c[4 * m + 0], c[4 * m + 1]);
                unsigned hi = (unsigned)pack_fp8x2(c[4 * m + 2], c[4 * m + 3]);
                pk[m] = lo | (hi << 16);
            }
            uint4* zd = (uint4*)&z0[((size_t)gr << 6) + (cb >> 1)];
            zd[0] = make_uint4(pk[0], pk[1], pk[2], pk[3]);
            zd[1] = make_uint4(pk[4], pk[5], pk[6], pk[7]);
            unsigned am[16];
#pragma unroll
            for (int m = 0; m < 16; ++m)
                am[m] = pack_bf16x2(A_ * c[2 * m], A_ * c[2 * m + 1]);
            uint4* ad = (uint4*)&ah[((size_t)gr << 6) + (cb >> 1)];
            ad[0] = make_uint4(am[0],  am[1],  am[2],  am[3]);
            ad[1] = make_uint4(am[4],  am[5],  am[6],  am[7]);
            ad[2] = make_uint4(am[8],  am[9],  am[10], am[11]);
            ad[3] = make_uint4(am[12], am[13], am[14], am[15]);
        }
    }
}

// ---------------- propagation hop ----------------
// IN8: 1 = fp8 input rows (128B), 0 = bf16 input rows (256B)
// OUTM: 0 = fp8, 1 = bf16, 3 = relu+bf16

template <int B, int IN8>
__device__ __forceinline__ void hop_batch(const void* __restrict__ zb,
                                          const int2* __restrict__ cw,
                                          int e, int lane,
                                          float& ax, float& ay,
                                          float& bx, float& by) {
    int2 p[B];
#pragma unroll
    for (int k = 0; k < B; ++k) p[k] = cw[e + k];
    unsigned zv[B];
#pragma unroll
    for (int k = 0; k < B; ++k) {
        if (IN8) zv[k] = ((const unsigned short*)zb)[((unsigned)p[k].x << 6) + lane];
        else     zv[k] = ((const unsigned*)zb)[((unsigned)p[k].x << 6) + lane];
    }
#pragma unroll
    for (int k = 0; k < B; ++k) {
        float wv = __int_as_float(p[k].y);
        float2 z = IN8 ? unpack_fp8x2((unsigned short)zv[k]) : unpack_bf16x2(zv[k]);
        if (k & 1) { bx = fmaf(wv, z.x, bx); by = fmaf(wv, z.y, by); }
        else       { ax = fmaf(wv, z.x, ax); ay = fmaf(wv, z.y, ay); }
    }
}

template <int IN8, int OUTM>
__global__ __launch_bounds__(256) void k_hop(const void* __restrict__ zin,
                                             const unsigned* __restrict__ ah,
                                             void* __restrict__ zout,
                                             const int* __restrict__ rp,
                                             const int2* __restrict__ cw, int N) {
    int wid  = (blockIdx.x * blockDim.x + threadIdx.x) >> 6;
    int lane = threadIdx.x & 63;
    if (wid >= N) return;

    int e   = __builtin_amdgcn_readfirstlane(rp[wid]);
    int end = __builtin_amdgcn_readfirstlane(rp[wid + 1]);

    float2 hh = unpack_bf16x2(ah[((size_t)wid << 6) + lane]);

    float ax = 0.f, ay = 0.f, bx = 0.f, by = 0.f;

    for (; e + 16 <= end; e += 16)
        hop_batch<16, IN8>(zin, cw, e, lane, ax, ay, bx, by);
    if (e + 8 <= end) { hop_batch<8, IN8>(zin, cw, e, lane, ax, ay, bx, by); e += 8; }
    if (e + 4 <= end) { hop_batch<4, IN8>(zin, cw, e, lane, ax, ay, bx, by); e += 4; }
    for (; e < end; ++e) {
        int2 p = cw[e];
        unsigned zv;
        if (IN8) zv = ((const unsigned short*)zin)[((unsigned)p.x << 6) + lane];
        else     zv = ((const unsigned*)zin)[((unsigned)p.x << 6) + lane];
        float2 z = IN8 ? unpack_fp8x2((unsigned short)zv) : unpack_bf16x2(zv);
        float wv = __int_as_float(p.y);
        ax = fmaf(wv, z.x, ax); ay = fmaf(wv, z.y, ay);
    }

    float ox = (ax + bx) + hh.x;
    float oy = (ay + by) + hh.y;
    if (OUTM == 0) {
        ((unsigned short*)zout)[((size_t)wid << 6) + lane] = pack_fp8x2(ox, oy);
    } else if (OUTM == 1) {
        ((unsigned*)zout)[((size_t)wid << 6) + lane] = pack_bf16x2(ox, oy);
    } else {
        ((unsigned*)zout)[((size_t)wid << 6) + lane] =
            pack_bf16x2(fmaxf(ox, 0.f), fmaxf(oy, 0.f));
    }
}

// ---------------- decode: out[j] = dot(z[e0[j]], z[e1[j]]), z bf16 ----------------

__global__ __launch_bounds__(256) void k_decode(const unsigned* __restrict__ z,
                                                const void* __restrict__ pos,
                                                const void* __restrict__ neg,
                                                float* __restrict__ out, int P, int Q,
                                                const int* __restrict__ flag) {
    int is64 = *flag;
    int t   = blockIdx.x * blockDim.x + threadIdx.x;
    int j   = t >> 4;
    int sub = t & 15;
    if (j >= P + Q) return;
    int a, b;
    if (j < P) { a = idx_at(pos, (size_t)j, is64); b = idx_at(pos, (size_t)P + j, is64); }
    else       { int jj = j - P; a = idx_at(neg, (size_t)jj, is64); b = idx_at(neg, (size_t)Q + jj, is64); }
    const uint4* za = (const uint4*)&z[(size_t)a << 6];
    const uint4* zb = (const uint4*)&z[(size_t)b << 6];
    uint4 va = za[sub];
    uint4 vb = zb[sub];
    float s = 0.f;
    {
        float2 xa, xb;
        xa = unpack_bf16x2(va.x); xb = unpack_bf16x2(vb.x);
        s += xa.x * xb.x + xa.y * xb.y;
        xa = unpack_bf16x2(va.y); xb = unpack_bf16x2(vb.y);
        s += xa.x * xb.x + xa.y * xb.y;
        xa = unpack_bf16x2(va.z); xb = unpack_bf16x2(vb.z);
        s += xa.x * xb.x + xa.y * xb.y;
        xa = unpack_bf16x2(va.w); xb = unpack_bf16x2(vb.w);
        s += xa.x * xb.x + xa.y * xb.y;
    }
#pragma unroll
    for (int off = 8; off >= 1; off >>= 1) s += __shfl_xor(s, off, 16);
    if (sub == 0) out[j] = s;
}

// ---------------- launch ----------------

extern "C" void kernel_launch(void* const* d_in, const int* in_sizes, int n_in,
                              void* d_out, int out_size, void* d_ws, size_t ws_size,
                              hipStream_t stream) {
    const float* x   = (const float*)d_in[0];
    const void*  ei  = d_in[1];
    const void*  pos = d_in[2];
    const void*  neg = d_in[3];
    const float* W1  = (const float*)d_in[4];
    const float* W2  = (const float*)d_in[5];
    float*       out = (float*)d_out;

    const int N = in_sizes[0] / Fin;
    const int E = in_sizes[1] / 2;
    const int P = in_sizes[2] / 2;
    const int Q = in_sizes[3] / 2;
    const int Etot = E + N;

    char*  ws  = (char*)d_ws;
    size_t off = 0;
    auto carve = [&](size_t bytes) -> void* {
        void* p = ws + off;
        off = (off + bytes + 511) & ~(size_t)511;
        return p;
    };
    unsigned short* f0   = (unsigned short*)carve((size_t)N * 64 * 2);
    unsigned short* f1   = (unsigned short*)carve((size_t)N * 64 * 2);
    unsigned*       zBF  = (unsigned*)carve((size_t)N * 64 * 4);   // bf16 penult
    unsigned*       zB2  = (unsigned*)carve((size_t)N * 64 * 4);   // bf16 final (decode)
    unsigned*       zRB  = (unsigned*)carve((size_t)N * 64 * 4);   // relu bf16 (L2 GEMM A)
    unsigned*       ah   = (unsigned*)carve((size_t)N * 64 * 4);
    unsigned short* Wt1  = (unsigned short*)carve((size_t)128 * 256 * 2);
    unsigned short* Wt2  = (unsigned short*)carve((size_t)128 * 128 * 2);
    float*          dinv = (float*)carve((size_t)N * 4);
    int*     cnt    = (int*)carve((size_t)N * 4);
    int*     rp     = (int*)carve((size_t)(N + 1) * 4);
    int*     cursor = (int*)carve((size_t)N * 4);
    int2*    cw     = (int2*)carve((size_t)Etot * 8);
    int      nb     = (N + 255) / 256;
    int*     bsum   = (int*)carve((size_t)nb * 4);
    int*     flag   = (int*)carve(4);
    (void)ws_size;

    const int gN = (N + 255) / 256;
    const int gE = (E + 255) / 256;

    k_detect<<<1, 256, 0, stream>>>((const int*)ei, 4096, flag);
    k_zero_i32<<<gN, 256, 0, stream>>>(cnt, N);
    k_count<<<gE, 256, 0, stream>>>(ei, E, cnt, flag);
    k_dinv<<<gN, 256, 0, stream>>>(cnt, dinv, N);
    k_scan1<<<nb, 256, 0, stream>>>(cnt, rp, bsum, N);
    k_scan2<<<1, 512, 0, stream>>>(bsum, nb);
    k_scan3<<<gN, 256, 0, stream>>>(rp, bsum, cursor, dinv, cw, N, Etot);
    k_place<<<gE, 256, 0, stream>>>(ei, E, rp, cursor, dinv, cw, flag);
    k_wt<<<(256 * 128 + 255) / 256, 256, 0, stream>>>(W1, Wt1, Fin);
    k_wt<<<(128 * 128 + 255) / 256, 256, 0, stream>>>(W2, Wt2, Hd);

    const int gGemm = (N + 63) / 64;
    const int gHop  = (N * 64 + 255) / 256;

    unsigned short* fb[2] = {f0, f1};

    // ---- layer 1 ----
    k_gemm_mfma<Fin, true><<<gGemm, 256, 0, stream>>>(x, Wt1, f0, ah, N);
    for (int k = 0; k < 8; ++k)
        k_hop<1, 0><<<gHop, 256, 0, stream>>>(fb[k & 1], ah, fb[(k + 1) & 1], rp, cw, N);
    k_hop<1, 1><<<gHop, 256, 0, stream>>>(f0, ah, zBF, rp, cw, N);
    k_hop<0, 3><<<gHop, 256, 0, stream>>>(zBF, ah, zRB, rp, cw, N);   // relu'd bf16 A for L2

    // ---- layer 2 ----
    k_gemm_mfma<Hd, false><<<gGemm, 256, 0, stream>>>(zRB, Wt2, f0, ah, N);
    for (int k = 0; k < 8; ++k)
        k_hop<1, 0><<<gHop, 256, 0, stream>>>(fb[k & 1], ah, fb[(k + 1) & 1], rp, cw, N);
    k_hop<1, 1><<<gHop, 256, 0, stream>>>(f0, ah, zBF, rp, cw, N);
    k_hop<0, 1><<<gHop, 256, 0, stream>>>(zBF, ah, zB2, rp, cw, N);

    // ---- decode (bf16 z) ----
    const int gDec = ((P + Q) * 16 + 255) / 256;
    k_decode<<<gDec, 256, 0, stream>>>(zB2, pos, neg, out, P, Q, flag);
}

// Round 10
// 1044.362 us; speedup vs baseline: 2.8098x; 1.0423x over previous
//
#include <hip/hip_runtime.h>

// APPNP link-prediction: N=100000, F=256, H=128, E=1.6M, K=10 x 2 layers.
// CSR-by-dst (self-loops folded, 0.9*norm pre-folded), gather-only SpMV hops.
// z stored fp8 e4m3 during hops (128B rows = 1 L2 line per gather); final hop
// of each layer reads fp8 and emits bf16 (relu'd for L2's GEMM input).
// GEMMs: v_mfma_f32_16x16x32_bf16. k_place: XCD-windowed for write locality.

constexpr int Hd = 128;
constexpr int Fin = 256;
constexpr float A_ = 0.1f;
constexpr float OMA = 0.9f;

typedef float vf2 __attribute__((ext_vector_type(2)));
typedef __bf16 bf16x8 __attribute__((ext_vector_type(8)));
typedef float f32x4 __attribute__((ext_vector_type(4)));

__device__ __forceinline__ int idx_at(const void* p, size_t i, int is64) {
    if (is64) return (int)((const long long*)p)[i];
    return ((const int*)p)[i];
}

__device__ __forceinline__ unsigned short bf16_of(float x) {
    unsigned u = __float_as_uint(x);
    return (unsigned short)((u + 0x7fffu + ((u >> 16) & 1u)) >> 16);
}

__device__ __forceinline__ unsigned pack_bf16x2(float x, float y) {
    unsigned ux = __float_as_uint(x);
    unsigned uy = __float_as_uint(y);
    ux = (ux + 0x7fffu + ((ux >> 16) & 1u)) >> 16;          // RNE
    uy = (uy + 0x7fffu + ((uy >> 16) & 1u)) & 0xffff0000u;  // RNE, keep high
    return ux | uy;
}

__device__ __forceinline__ float2 unpack_bf16x2(unsigned v) {
    float2 r;
    r.x = __uint_as_float(v << 16);
    r.y = __uint_as_float(v & 0xffff0000u);
    return r;
}

__device__ __forceinline__ unsigned short pack_fp8x2(float x, float y) {
    int v = __builtin_amdgcn_cvt_pk_fp8_f32(x, y, 0, false);   // low word
    return (unsigned short)(unsigned)v;
}

__device__ __forceinline__ float2 unpack_fp8x2(unsigned short v) {
    vf2 r = __builtin_amdgcn_cvt_pk_f32_fp8((int)(unsigned)v, false);
    float2 o;
    o.x = r[0];
    o.y = r[1];
    return o;
}

// ---------------- dtype probe ----------------
__global__ void k_detect(const int* __restrict__ p, int npairs, int* __restrict__ flag) {
    __shared__ int any32;
    if (threadIdx.x == 0) any32 = 0;
    __syncthreads();
    for (int i = threadIdx.x; i < npairs; i += blockDim.x)
        if (p[2 * i + 1] != 0) any32 = 1;
    __syncthreads();
    if (threadIdx.x == 0) *flag = any32 ? 0 : 1;   // 1 => int64
}

// ---------------- preprocessing ----------------

__global__ void k_zero_i32(int* __restrict__ p, int n) {
    int i = blockIdx.x * blockDim.x + threadIdx.x;
    if (i < n) p[i] = 0;
}

__global__ void k_count(const void* __restrict__ ei, int E, int* __restrict__ cnt,
                        const int* __restrict__ flag) {
    int is64 = *flag;
    int e = blockIdx.x * blockDim.x + threadIdx.x;
    if (e < E) {
        int d = idx_at(ei, (size_t)E + e, is64);
        atomicAdd(&cnt[d], 1);
    }
}

__global__ void k_dinv(const int* __restrict__ cnt, float* __restrict__ dinv, int N) {
    int i = blockIdx.x * blockDim.x + threadIdx.x;
    if (i < N) dinv[i] = rsqrtf((float)(cnt[i] + 1));
}

__global__ void k_scan1(const int* __restrict__ cnt, int* __restrict__ rp,
                        int* __restrict__ bsum, int N) {
    __shared__ int s[256];
    int t = threadIdx.x;
    int i = blockIdx.x * 256 + t;
    int v = (i < N) ? (cnt[i] + 1) : 0;   // +1 self-loop slot
    s[t] = v;
    __syncthreads();
    for (int off = 1; off < 256; off <<= 1) {
        int add = (t >= off) ? s[t - off] : 0;
        __syncthreads();
        s[t] += add;
        __syncthreads();
    }
    if (i < N) rp[i] = s[t] - v;
    if (t == 255) bsum[blockIdx.x] = s[255];
}

__global__ void k_scan2(int* __restrict__ bsum, int nb) {
    __shared__ int s[512];
    int t = threadIdx.x;
    int v = (t < nb) ? bsum[t] : 0;
    s[t] = v;
    __syncthreads();
    for (int off = 1; off < 512; off <<= 1) {
        int add = (t >= off) ? s[t - off] : 0;
        __syncthreads();
        s[t] += add;
        __syncthreads();
    }
    if (t < nb) bsum[t] = s[t] - v;
}

__global__ void k_scan3(int* __restrict__ rp, const int* __restrict__ bsum,
                        int* __restrict__ cursor, const float* __restrict__ dinv,
                        int2* __restrict__ cw, int N, int Etot) {
    int i = blockIdx.x * blockDim.x + threadIdx.x;
    if (i < N) {
        int r = rp[i] + bsum[i >> 8];
        rp[i] = r;
        cursor[i] = 1;
        float d = dinv[i];
        int2 p;
        p.x = i;
        p.y = __float_as_int(OMA * d * d);
        cw[r] = p;   // self-loop first in each row
    }
    if (i == 0) rp[N] = Etot;
}

// XCD-windowed place: group g = blockIdx.x % 8 handles dst in [g*N/8,(g+1)*N/8).
// All cw writes of a window come from one XCD's CUs -> lines fill in its L2.
__global__ __launch_bounds__(256) void k_place_xcd(const void* __restrict__ ei, int E,
                                                   const int* __restrict__ rp,
                                                   int* __restrict__ cursor,
                                                   const float* __restrict__ dinv,
                                                   int2* __restrict__ cw,
                                                   const int* __restrict__ flag, int N) {
    const int is64 = *flag;
    const int g    = blockIdx.x & 7;            // XCD-affinity heuristic
    const int gb   = blockIdx.x >> 3;           // group-local block id
    const int nblk = gridDim.x >> 3;            // blocks per group
    const int lo   = (int)(((long long)g * N) >> 3);
    const int hi   = (int)(((long long)(g + 1) * N) >> 3);
    for (int e = gb * 256 + threadIdx.x; e < E; e += nblk * 256) {
        int d = idx_at(ei, (size_t)E + e, is64);
        if (d >= lo && d < hi) {
            int s = idx_at(ei, (size_t)e, is64);
            int pos = rp[d] + atomicAdd(&cursor[d], 1);
            int2 p;
            p.x = s;
            p.y = __float_as_int(OMA * dinv[s] * dinv[d]);
            cw[pos] = p;
        }
    }
}

// ---------------- W transpose+cvt: Wt[c][k] = bf16(W[k][c]), W is [K][128] ----------------
__global__ void k_wt(const float* __restrict__ W, unsigned short* __restrict__ Wt, int K) {
    int i = blockIdx.x * blockDim.x + threadIdx.x;
    if (i < K * 128) {
        int k = i >> 7, c = i & 127;
        Wt[c * K + k] = bf16_of(W[i]);
    }
}

// ---------------- MFMA GEMM: z0 fp8 + alpha*h bf16 from A[N][KTOT] @ W[KTOT][128] ----------------

template <int KTOT, bool AF32>
__global__ __launch_bounds__(256) void k_gemm_mfma(const void* __restrict__ Ap,
                                                   const unsigned short* __restrict__ Wt,
                                                   unsigned short* __restrict__ z0,
                                                   unsigned* __restrict__ ah, int N) {
    __shared__ __align__(16) char smem[64 * 132 * 4];
    unsigned short (*As)[40] = (unsigned short(*)[40])smem;            // 64 x 32 (+8 pad)
    unsigned short (*Bs)[40] = (unsigned short(*)[40])(smem + 5120);   // 128 x 32 (+8 pad), [col][k]
    float (*Cs)[132] = (float(*)[132])smem;

    const int t    = threadIdx.x;
    const int lane = t & 63;
    const int w    = t >> 6;
    const int wr   = w >> 1;
    const int wc   = w & 1;
    const int r0   = blockIdx.x * 64;

    f32x4 acc[2][4];
#pragma unroll
    for (int i = 0; i < 2; ++i)
#pragma unroll
        for (int j = 0; j < 4; ++j)
#pragma unroll
            for (int q = 0; q < 4; ++q) acc[i][j][q] = 0.f;

    const int arow = t >> 2;
    const int akc  = (t & 3) * 8;
    const int bcol = t >> 1;
    const int bkc  = (t & 1) * 16;

    for (int k0 = 0; k0 < KTOT; k0 += 32) {
        {
            int gr = r0 + arow;
            if (AF32) {
                uint4 s = make_uint4(0, 0, 0, 0);
                if (gr < N) {
                    const float* a = (const float*)Ap + (size_t)gr * KTOT + k0 + akc;
                    float4 v0 = *(const float4*)a;
                    float4 v1 = *(const float4*)(a + 4);
                    s.x = pack_bf16x2(v0.x, v0.y);
                    s.y = pack_bf16x2(v0.z, v0.w);
                    s.z = pack_bf16x2(v1.x, v1.y);
                    s.w = pack_bf16x2(v1.z, v1.w);
                }
                *(uint4*)&As[arow][akc] = s;
            } else {
                uint4 s = make_uint4(0, 0, 0, 0);
                if (gr < N) s = *(const uint4*)((const unsigned short*)Ap + (size_t)gr * KTOT + k0 + akc);
                *(uint4*)&As[arow][akc] = s;
            }
        }
        {
            const unsigned short* wsrc = Wt + (size_t)bcol * KTOT + k0 + bkc;
            *(uint4*)&Bs[bcol][bkc]     = *(const uint4*)wsrc;
            *(uint4*)&Bs[bcol][bkc + 8] = *(const uint4*)(wsrc + 8);
        }
        __syncthreads();
        {
            const int kblk = (lane >> 4) * 8;
            const int l15  = lane & 15;
            bf16x8 af[2], bfr[4];
#pragma unroll
            for (int i = 0; i < 2; ++i)
                af[i] = *(const bf16x8*)&As[wr * 32 + i * 16 + l15][kblk];
#pragma unroll
            for (int j = 0; j < 4; ++j)
                bfr[j] = *(const bf16x8*)&Bs[wc * 64 + j * 16 + l15][kblk];
#pragma unroll
            for (int i = 0; i < 2; ++i)
#pragma unroll
                for (int j = 0; j < 4; ++j)
                    acc[i][j] = __builtin_amdgcn_mfma_f32_16x16x32_bf16(af[i], bfr[j], acc[i][j], 0, 0, 0);
        }
        __syncthreads();
    }

    {
        const int l15 = lane & 15;
        const int rq  = (lane >> 4) * 4;
#pragma unroll
        for (int i = 0; i < 2; ++i)
#pragma unroll
            for (int j = 0; j < 4; ++j)
#pragma unroll
                for (int q = 0; q < 4; ++q)
                    Cs[wr * 32 + i * 16 + rq + q][wc * 64 + j * 16 + l15] = acc[i][j][q];
    }
    __syncthreads();
    {
        const int row = t >> 2;
        const int cb  = (t & 3) * 32;
        const int gr  = r0 + row;
        if (gr < N) {
            float c[32];
#pragma unroll
            for (int m = 0; m < 8; ++m) {
                float4 v = *(const float4*)&Cs[row][cb + m * 4];
                c[m * 4 + 0] = v.x; c[m * 4 + 1] = v.y; c[m * 4 + 2] = v.z; c[m * 4 + 3] = v.w;
            }
            unsigned pk[8];
#pragma unroll
            for (int m = 0; m < 8; ++m) {
                unsigned lo = (unsigned)pack_fp8x2(c[4 * m + 0], c[4 * m + 1]);
                unsigned hi = (unsigned)pack_fp8x2(c[4 * m + 2], c[4 * m + 3]);
                pk[m] = lo | (hi << 16);
            }
            uint4* zd = (uint4*)&z0[((size_t)gr << 6) + (cb >> 1)];
            zd[0] = make_uint4(pk[0], pk[1], pk[2], pk[3]);
            zd[1] = make_uint4(pk[4], pk[5], pk[6], pk[7]);
            unsigned am[16];
#pragma unroll
            for (int m = 0; m < 16; ++m)
                am[m] = pack_bf16x2(A_ * c[2 * m], A_ * c[2 * m + 1]);
            uint4* ad = (uint4*)&ah[((size_t)gr << 6) + (cb >> 1)];
            ad[0] = make_uint4(am[0],  am[1],  am[2],  am[3]);
            ad[1] = make_uint4(am[4],  am[5],  am[6],  am[7]);
            ad[2] = make_uint4(am[8],  am[9],  am[10], am[11]);
            ad[3] = make_uint4(am[12], am[13], am[14], am[15]);
        }
    }
}

// ---------------- propagation hop ----------------
// IN8: 1 = fp8 input rows (128B), 0 = bf16 (256B). OUTM: 0 fp8, 1 bf16, 3 relu+bf16.

template <int B, int IN8>
__device__ __forceinline__ void hop_batch(const void* __restrict__ zb,
                                          const int2* __restrict__ cw,
                                          int e, int lane,
                                          float& ax, float& ay,
                                          float& bx, float& by) {
    int2 p[B];
#pragma unroll
    for (int k = 0; k < B; ++k) p[k] = cw[e + k];
    unsigned zv[B];
#pragma unroll
    for (int k = 0; k < B; ++k) {
        if (IN8) zv[k] = ((const unsigned short*)zb)[((unsigned)p[k].x << 6) + lane];
        else     zv[k] = ((const unsigned*)zb)[((unsigned)p[k].x << 6) + lane];
    }
#pragma unroll
    for (int k = 0; k < B; ++k) {
        float wv = __int_as_float(p[k].y);
        float2 z = IN8 ? unpack_fp8x2((unsigned short)zv[k]) : unpack_bf16x2(zv[k]);
        if (k & 1) { bx = fmaf(wv, z.x, bx); by = fmaf(wv, z.y, by); }
        else       { ax = fmaf(wv, z.x, ax); ay = fmaf(wv, z.y, ay); }
    }
}

template <int IN8, int OUTM>
__global__ __launch_bounds__(256) void k_hop(const void* __restrict__ zin,
                                             const unsigned* __restrict__ ah,
                                             void* __restrict__ zout,
                                             const int* __restrict__ rp,
                                             const int2* __restrict__ cw, int N) {
    int wid  = (blockIdx.x * blockDim.x + threadIdx.x) >> 6;
    int lane = threadIdx.x & 63;
    if (wid >= N) return;

    int e   = __builtin_amdgcn_readfirstlane(rp[wid]);
    int end = __builtin_amdgcn_readfirstlane(rp[wid + 1]);

    float2 hh = unpack_bf16x2(ah[((size_t)wid << 6) + lane]);

    float ax = 0.f, ay = 0.f, bx = 0.f, by = 0.f;

    for (; e + 16 <= end; e += 16)
        hop_batch<16, IN8>(zin, cw, e, lane, ax, ay, bx, by);
    if (e + 8 <= end) { hop_batch<8, IN8>(zin, cw, e, lane, ax, ay, bx, by); e += 8; }
    if (e + 4 <= end) { hop_batch<4, IN8>(zin, cw, e, lane, ax, ay, bx, by); e += 4; }
    for (; e < end; ++e) {
        int2 p = cw[e];
        unsigned zv;
        if (IN8) zv = ((const unsigned short*)zin)[((unsigned)p.x << 6) + lane];
        else     zv = ((const unsigned*)zin)[((unsigned)p.x << 6) + lane];
        float2 z = IN8 ? unpack_fp8x2((unsigned short)zv) : unpack_bf16x2(zv);
        float wv = __int_as_float(p.y);
        ax = fmaf(wv, z.x, ax); ay = fmaf(wv, z.y, ay);
    }

    float ox = (ax + bx) + hh.x;
    float oy = (ay + by) + hh.y;
    if (OUTM == 0) {
        ((unsigned short*)zout)[((size_t)wid << 6) + lane] = pack_fp8x2(ox, oy);
    } else if (OUTM == 1) {
        ((unsigned*)zout)[((size_t)wid << 6) + lane] = pack_bf16x2(ox, oy);
    } else {
        ((unsigned*)zout)[((size_t)wid << 6) + lane] =
            pack_bf16x2(fmaxf(ox, 0.f), fmaxf(oy, 0.f));
    }
}

// ---------------- decode: out[j] = dot(z[e0[j]], z[e1[j]]), z bf16 ----------------

__global__ __launch_bounds__(256) void k_decode(const unsigned* __restrict__ z,
                                                const void* __restrict__ pos,
                                                const void* __restrict__ neg,
                                                float* __restrict__ out, int P, int Q,
                                                const int* __restrict__ flag) {
    int is64 = *flag;
    int t   = blockIdx.x * blockDim.x + threadIdx.x;
    int j   = t >> 4;
    int sub = t & 15;
    if (j >= P + Q) return;
    int a, b;
    if (j < P) { a = idx_at(pos, (size_t)j, is64); b = idx_at(pos, (size_t)P + j, is64); }
    else       { int jj = j - P; a = idx_at(neg, (size_t)jj, is64); b = idx_at(neg, (size_t)Q + jj, is64); }
    const uint4* za = (const uint4*)&z[(size_t)a << 6];
    const uint4* zb = (const uint4*)&z[(size_t)b << 6];
    uint4 va = za[sub];
    uint4 vb = zb[sub];
    float s = 0.f;
    {
        float2 xa, xb;
        xa = unpack_bf16x2(va.x); xb = unpack_bf16x2(vb.x);
        s += xa.x * xb.x + xa.y * xb.y;
        xa = unpack_bf16x2(va.y); xb = unpack_bf16x2(vb.y);
        s += xa.x * xb.x + xa.y * xb.y;
        xa = unpack_bf16x2(va.z); xb = unpack_bf16x2(vb.z);
        s += xa.x * xb.x + xa.y * xb.y;
        xa = unpack_bf16x2(va.w); xb = unpack_bf16x2(vb.w);
        s += xa.x * xb.x + xa.y * xb.y;
    }
#pragma unroll
    for (int off = 8; off >= 1; off >>= 1) s += __shfl_xor(s, off, 16);
    if (sub == 0) out[j] = s;
}

// ---------------- launch ----------------

extern "C" void kernel_launch(void* const* d_in, const int* in_sizes, int n_in,
                              void* d_out, int out_size, void* d_ws, size_t ws_size,
                              hipStream_t stream) {
    const float* x   = (const float*)d_in[0];
    const void*  ei  = d_in[1];
    const void*  pos = d_in[2];
    const void*  neg = d_in[3];
    const float* W1  = (const float*)d_in[4];
    const float* W2  = (const float*)d_in[5];
    float*       out = (float*)d_out;

    const int N = in_sizes[0] / Fin;
    const int E = in_sizes[1] / 2;
    const int P = in_sizes[2] / 2;
    const int Q = in_sizes[3] / 2;
    const int Etot = E + N;

    char*  ws  = (char*)d_ws;
    size_t off = 0;
    auto carve = [&](size_t bytes) -> void* {
        void* p = ws + off;
        off = (off + bytes + 511) & ~(size_t)511;
        return p;
    };
    unsigned short* f0   = (unsigned short*)carve((size_t)N * 64 * 2);
    unsigned short* f1   = (unsigned short*)carve((size_t)N * 64 * 2);
    unsigned*       zB2  = (unsigned*)carve((size_t)N * 64 * 4);   // bf16 final (decode)
    unsigned*       zRB  = (unsigned*)carve((size_t)N * 64 * 4);   // relu bf16 (L2 GEMM A)
    unsigned*       ah   = (unsigned*)carve((size_t)N * 64 * 4);
    unsigned short* Wt1  = (unsigned short*)carve((size_t)128 * 256 * 2);
    unsigned short* Wt2  = (unsigned short*)carve((size_t)128 * 128 * 2);
    float*          dinv = (float*)carve((size_t)N * 4);
    int*     cnt    = (int*)carve((size_t)N * 4);
    int*     rp     = (int*)carve((size_t)(N + 1) * 4);
    int*     cursor = (int*)carve((size_t)N * 4);
    int2*    cw     = (int2*)carve((size_t)Etot * 8);
    int      nb     = (N + 255) / 256;
    int*     bsum   = (int*)carve((size_t)nb * 4);
    int*     flag   = (int*)carve(4);
    (void)ws_size;

    const int gN = (N + 255) / 256;
    const int gE = (E + 255) / 256;

    k_detect<<<1, 256, 0, stream>>>((const int*)ei, 4096, flag);
    k_zero_i32<<<gN, 256, 0, stream>>>(cnt, N);
    k_count<<<gE, 256, 0, stream>>>(ei, E, cnt, flag);
    k_dinv<<<gN, 256, 0, stream>>>(cnt, dinv, N);
    k_scan1<<<nb, 256, 0, stream>>>(cnt, rp, bsum, N);
    k_scan2<<<1, 512, 0, stream>>>(bsum, nb);
    k_scan3<<<gN, 256, 0, stream>>>(rp, bsum, cursor, dinv, cw, N, Etot);
    k_place_xcd<<<1024, 256, 0, stream>>>(ei, E, rp, cursor, dinv, cw, flag, N);
    k_wt<<<(256 * 128 + 255) / 256, 256, 0, stream>>>(W1, Wt1, Fin);
    k_wt<<<(128 * 128 + 255) / 256, 256, 0, stream>>>(W2, Wt2, Hd);

    const int gGemm = (N + 63) / 64;
    const int gHop  = (N * 64 + 255) / 256;

    unsigned short* fb[2] = {f0, f1};

    // ---- layer 1: GEMM -> 9 fp8 hops -> final hop reads fp8, writes relu-bf16 ----
    k_gemm_mfma<Fin, true><<<gGemm, 256, 0, stream>>>(x, Wt1, f0, ah, N);
    for (int k = 0; k < 9; ++k)
        k_hop<1, 0><<<gHop, 256, 0, stream>>>(fb[k & 1], ah, fb[(k + 1) & 1], rp, cw, N);
    k_hop<1, 3><<<gHop, 256, 0, stream>>>(f1, ah, zRB, rp, cw, N);

    // ---- layer 2: GEMM -> 9 fp8 hops -> final hop reads fp8, writes bf16 ----
    k_gemm_mfma<Hd, false><<<gGemm, 256, 0, stream>>>(zRB, Wt2, f0, ah, N);
    for (int k = 0; k < 9; ++k)
        k_hop<1, 0><<<gHop, 256, 0, stream>>>(fb[k & 1], ah, fb[(k + 1) & 1], rp, cw, N);
    k_hop<1, 1><<<gHop, 256, 0, stream>>>(f1, ah, zB2, rp, cw, N);

    // ---- decode (bf16 z) ----
    const int gDec = ((P + Q) * 16 + 255) / 256;
    k_decode<<<gDec, 256, 0, stream>>>(zB2, pos, neg, out, P, Q, flag);
}